// Round 1
// baseline (172.075 us; speedup 1.0000x reference)
//
#include <hip/hip_runtime.h>
#include <stdint.h>

// DistMatchLayer: for each point in coords_a, find TOPK=5 nearest points in
// coords_b (stable ties -> lower index), weight by w = 0.5 - min(dist/32, 0.5),
// output [feat_a | sum_t w_t * feat_b[idx_t]].
//
// Key insight: coords are ints in [0,32) -> d2 is an exact integer <= 2883
// (12 bits). key = (d2 << 13) | j reproduces jax.lax.top_k's stable ordering
// with a single unsigned compare.

namespace {
constexpr int kB = 4;
constexpr int kNa = 8192;
constexpr int kNb = 8192;
constexpr int kC = 64;
constexpr int kWaves = 4;               // 4 waves/block, one output row per wave
constexpr int kThreads = kWaves * 64;   // 256
constexpr int kBlocksPerBatch = kNa / kWaves;  // 2048
}

__device__ __forceinline__ uint32_t umin_(uint32_t a, uint32_t b) { return a < b ? a : b; }
__device__ __forceinline__ uint32_t umax_(uint32_t a, uint32_t b) { return a > b ? a : b; }
__device__ __forceinline__ void cswap_(uint32_t& a, uint32_t& b) {
    uint32_t lo = umin_(a, b);
    uint32_t hi = umax_(a, b);
    a = lo; b = hi;
}

__global__ __launch_bounds__(kThreads, 4)
void dist_match_kernel(const int* __restrict__ coords_a,
                       const int* __restrict__ coords_b,
                       const float* __restrict__ feat_a,
                       const float* __restrict__ feat_b,
                       float* __restrict__ out)
{
    __shared__ int spack[kNb];  // 32 KB: coords_b packed x|y<<5|z<<10

    const int b = blockIdx.x / kBlocksPerBatch;
    const int rowBase = (blockIdx.x % kBlocksPerBatch) * kWaves;
    const int tid = threadIdx.x;
    const int lane = tid & 63;
    const int wave = tid >> 6;

    // ---- stage packed coords_b for this batch into LDS ----
    const int* cb = coords_b + (size_t)b * kNb * 3;
    for (int j = tid; j < kNb; j += kThreads) {
        const int x = cb[3 * j + 0];
        const int y = cb[3 * j + 1];
        const int z = cb[3 * j + 2];
        spack[j] = x | (y << 5) | (z << 10);
    }
    __syncthreads();

    const int row = rowBase + wave;
    const int* ca = coords_a + ((size_t)b * kNa + row) * 3;
    const int ax = ca[0], ay = ca[1], az = ca[2];

    // ---- per-lane scan: sorted top-5 keys (smallest first) ----
    uint32_t t0 = 0xFFFFFFFFu, t1 = t0, t2 = t0, t3 = t0, t4 = t0;

    for (int k = 0; k < kNb / 256; ++k) {            // 32 iters
        const int base = k * 256 + lane * 4;
        const int4 p4 = *reinterpret_cast<const int4*>(spack + base);  // ds_read_b128
        const int ps[4] = {p4.x, p4.y, p4.z, p4.w};
        #pragma unroll
        for (int u = 0; u < 4; ++u) {
            const int p = ps[u];
            const int dx = ax - (p & 31);
            const int dy = ay - ((p >> 5) & 31);
            const int dz = az - ((p >> 10) & 31);
            const uint32_t d2 = (uint32_t)(dx * dx + dy * dy + dz * dz);
            const uint32_t key = (d2 << 13) | (uint32_t)(base + u);
            if (key < t4) {                           // rare after warm-up
                t4 = key;
                cswap_(t3, t4);
                cswap_(t2, t3);
                cswap_(t1, t2);
                cswap_(t0, t1);
            }
        }
    }

    // ---- butterfly merge of sorted 5-lists across the 64 lanes ----
    #pragma unroll
    for (int s = 1; s < 64; s <<= 1) {
        const uint32_t b0 = (uint32_t)__shfl_xor((int)t0, s);
        const uint32_t b1 = (uint32_t)__shfl_xor((int)t1, s);
        const uint32_t b2 = (uint32_t)__shfl_xor((int)t2, s);
        const uint32_t b3 = (uint32_t)__shfl_xor((int)t3, s);
        const uint32_t b4 = (uint32_t)__shfl_xor((int)t4, s);
        // i-th smallest of the union of two sorted 5-lists:
        // c_i = min( min_{j=0..i-1} max(a_j, b_{i-1-j}), a_i, b_i )
        const uint32_t c0 = umin_(t0, b0);
        const uint32_t c1 = umin_(umin_(umax_(t0, b0), t1), b1);
        const uint32_t c2 = umin_(umin_(umax_(t0, b1), umax_(t1, b0)), umin_(t2, b2));
        const uint32_t c3 = umin_(umin_(umax_(t0, b2), umax_(t1, b1)),
                                  umin_(umax_(t2, b0), umin_(t3, b3)));
        const uint32_t c4 = umin_(umin_(umax_(t0, b3), umax_(t1, b2)),
                                  umin_(umin_(umax_(t2, b1), umax_(t3, b0)),
                                        umin_(t4, b4)));
        t0 = c0; t1 = c1; t2 = c2; t3 = c3; t4 = c4;
    }
    // now every lane holds the global sorted top-5 for this row

    // ---- weights + gather: lane == channel ----
    const float* fb = feat_b + (size_t)b * kNb * kC;
    const uint32_t keys[5] = {t0, t1, t2, t3, t4};
    float acc = 0.0f;
    #pragma unroll
    for (int t = 0; t < 5; ++t) {
        const uint32_t key = keys[t];
        const int j = (int)(key & 8191u);
        const float dist = sqrtf((float)(key >> 13)) * (1.0f / 32.0f);
        const float w = 0.5f - fminf(dist, 0.5f);
        acc += w * fb[(size_t)j * kC + lane];         // coalesced 256B per row
    }

    const size_t orow = ((size_t)b * kNa + row) * (2 * kC);
    out[orow + lane] = feat_a[((size_t)b * kNa + row) * kC + lane];
    out[orow + kC + lane] = acc;
}

extern "C" void kernel_launch(void* const* d_in, const int* in_sizes, int n_in,
                              void* d_out, int out_size, void* d_ws, size_t ws_size,
                              hipStream_t stream) {
    const int* coords_a = (const int*)d_in[0];
    const int* coords_b = (const int*)d_in[1];
    const float* feat_a = (const float*)d_in[2];
    const float* feat_b = (const float*)d_in[3];
    float* out = (float*)d_out;

    const int grid = kB * kBlocksPerBatch;  // 8192 blocks
    dist_match_kernel<<<grid, kThreads, 0, stream>>>(coords_a, coords_b,
                                                     feat_a, feat_b, out);
}

// Round 2
// 170.523 us; speedup vs baseline: 1.0091x; 1.0091x over previous
//
#include <hip/hip_runtime.h>
#include <stdint.h>

// DistMatchLayer: for each point in coords_a, find TOPK=5 nearest points in
// coords_b (stable ties -> lower index), weight by w = 0.5 - min(dist/32, 0.5),
// output [feat_a | sum_t w_t * feat_b[idx_t]].
//
// Coords are ints in [0,32) -> d2 is an exact integer <= 2883.
// Scan-phase key: (d2<<9) | jlocal, jlocal = 4k+u (wave-uniform SGPR -> the
// key build is a single v_lshl_or_b32). Full key (d2<<13)|j rebuilt for the
// 5 survivors only; j is monotone in jlocal so jax.lax.top_k's stable tie
// order is reproduced exactly.
// Insert is a branchless 9-op min/max network (wave-any made the branch
// useless: P(any of 64 lanes inserts) ~= 1 for the whole 512-cand scan).

namespace {
constexpr int kB = 4;
constexpr int kNa = 8192;
constexpr int kNb = 8192;
constexpr int kC = 64;
constexpr int kWaves = 4;               // 4 waves/block, one output row per wave
constexpr int kThreads = kWaves * 64;   // 256
constexpr int kBlocksPerBatch = kNa / kWaves;  // 2048
}

__device__ __forceinline__ uint32_t umin_(uint32_t a, uint32_t b) { return a < b ? a : b; }
__device__ __forceinline__ uint32_t umax_(uint32_t a, uint32_t b) { return a > b ? a : b; }

__global__ __launch_bounds__(kThreads, 4)
void dist_match_kernel(const int* __restrict__ coords_a,
                       const int* __restrict__ coords_b,
                       const float* __restrict__ feat_a,
                       const float* __restrict__ feat_b,
                       float* __restrict__ out)
{
    __shared__ int spack[kNb];  // 32 KB: coords_b packed x|y<<5|z<<10

    const int b = blockIdx.x / kBlocksPerBatch;
    const int rowBase = (blockIdx.x % kBlocksPerBatch) * kWaves;
    const int tid = threadIdx.x;
    const int lane = tid & 63;
    const int wave = tid >> 6;

    // ---- stage packed coords_b for this batch into LDS ----
    const int* cb = coords_b + (size_t)b * kNb * 3;
    for (int j = tid; j < kNb; j += kThreads) {
        const int x = cb[3 * j + 0];
        const int y = cb[3 * j + 1];
        const int z = cb[3 * j + 2];
        spack[j] = x | (y << 5) | (z << 10);
    }
    __syncthreads();

    const int row = rowBase + wave;
    const int* ca = coords_a + ((size_t)b * kNa + row) * 3;
    const int ax = ca[0], ay = ca[1], az = ca[2];

    // ---- per-lane branchless scan: sorted top-5 scan-keys (smallest first) ----
    uint32_t t0 = 0xFFFFFFFFu, t1 = t0, t2 = t0, t3 = t0, t4 = t0;

    for (int k = 0; k < kNb / 256; ++k) {            // 32 iters, 4 cands each
        const int base = k * 256 + lane * 4;
        const int4 p4 = *reinterpret_cast<const int4*>(spack + base);  // ds_read_b128
        const int ps[4] = {p4.x, p4.y, p4.z, p4.w};
        #pragma unroll
        for (int u = 0; u < 4; ++u) {
            const int p = ps[u];
            const int dx = ax - (p & 31);
            const int dy = ay - ((p >> 5) & 31);
            const int dz = az - (p >> 10);           // p < 2^15, no mask needed
            const uint32_t d2 = (uint32_t)(__mul24(dx, dx) + __mul24(dy, dy)
                                           + __mul24(dz, dz));
            // jlocal = 4k+u is wave-uniform -> SGPR; one v_lshl_or_b32
            const uint32_t key = (d2 << 9) | (uint32_t)(4 * k + u);
            // branchless sorted insert (5 min + 4 max)
            const uint32_t m0 = umax_(t0, key); t0 = umin_(t0, key);
            const uint32_t m1 = umax_(t1, m0);  t1 = umin_(t1, m0);
            const uint32_t m2 = umax_(t2, m1);  t2 = umin_(t2, m1);
            const uint32_t m3 = umax_(t3, m2);  t3 = umin_(t3, m2);
            t4 = umin_(t4, m3);
        }
    }

    // ---- rebuild full keys (d2<<13)|j for the 5 survivors ----
    // jlocal = 4k+u  ->  j = k*256 + lane*4 + u  (disjoint bit fields)
    const uint32_t laneBits = (uint32_t)lane << 2;
    {
        uint32_t* ts[5] = {&t0, &t1, &t2, &t3, &t4};
        #pragma unroll
        for (int t = 0; t < 5; ++t) {
            const uint32_t key = *ts[t];
            const uint32_t jl = key & 511u;
            const uint32_t d2 = key >> 9;
            *ts[t] = (d2 << 13) | ((jl >> 2) << 8) | laneBits | (jl & 3u);
        }
    }

    // ---- butterfly merge of sorted 5-lists across the 64 lanes ----
    #pragma unroll
    for (int s = 1; s < 64; s <<= 1) {
        const uint32_t b0 = (uint32_t)__shfl_xor((int)t0, s);
        const uint32_t b1 = (uint32_t)__shfl_xor((int)t1, s);
        const uint32_t b2 = (uint32_t)__shfl_xor((int)t2, s);
        const uint32_t b3 = (uint32_t)__shfl_xor((int)t3, s);
        const uint32_t b4 = (uint32_t)__shfl_xor((int)t4, s);
        // i-th smallest of the union of two sorted 5-lists
        const uint32_t c0 = umin_(t0, b0);
        const uint32_t c1 = umin_(umin_(umax_(t0, b0), t1), b1);
        const uint32_t c2 = umin_(umin_(umax_(t0, b1), umax_(t1, b0)), umin_(t2, b2));
        const uint32_t c3 = umin_(umin_(umax_(t0, b2), umax_(t1, b1)),
                                  umin_(umax_(t2, b0), umin_(t3, b3)));
        const uint32_t c4 = umin_(umin_(umax_(t0, b3), umax_(t1, b2)),
                                  umin_(umin_(umax_(t2, b1), umax_(t3, b0)),
                                        umin_(t4, b4)));
        t0 = c0; t1 = c1; t2 = c2; t3 = c3; t4 = c4;
    }
    // now every lane holds the global sorted top-5 for this row

    // ---- weights + gather: lane == channel ----
    const float* fb = feat_b + (size_t)b * kNb * kC;
    const uint32_t keys[5] = {t0, t1, t2, t3, t4};
    float acc = 0.0f;
    #pragma unroll
    for (int t = 0; t < 5; ++t) {
        const uint32_t key = keys[t];
        const int j = (int)(key & 8191u);
        const float dist = sqrtf((float)(key >> 13)) * (1.0f / 32.0f);
        const float w = 0.5f - fminf(dist, 0.5f);
        acc += w * fb[(size_t)j * kC + lane];         // coalesced 256B per row
    }

    const size_t orow = ((size_t)b * kNa + row) * (2 * kC);
    out[orow + lane] = feat_a[((size_t)b * kNa + row) * kC + lane];
    out[orow + kC + lane] = acc;
}

extern "C" void kernel_launch(void* const* d_in, const int* in_sizes, int n_in,
                              void* d_out, int out_size, void* d_ws, size_t ws_size,
                              hipStream_t stream) {
    const int* coords_a = (const int*)d_in[0];
    const int* coords_b = (const int*)d_in[1];
    const float* feat_a = (const float*)d_in[2];
    const float* feat_b = (const float*)d_in[3];
    float* out = (float*)d_out;

    const int grid = kB * kBlocksPerBatch;  // 8192 blocks
    dist_match_kernel<<<grid, kThreads, 0, stream>>>(coords_a, coords_b,
                                                     feat_a, feat_b, out);
}

// Round 3
// 118.544 us; speedup vs baseline: 1.4516x; 1.4385x over previous
//
#include <hip/hip_runtime.h>
#include <stdint.h>

// DistMatchLayer: per coords_a point, top-5 nearest in coords_b (stable ties),
// w = 0.5 - min(dist/32, 0.5), out = [feat_a | sum w*feat_b[idx]].
//
// d2 is an exact small integer (coords in [0,32)): computed with TWO
// v_dot4_i32_i8 ops on byte-packed coords:
//   dot1 = sdot4(bytes(-2ax,-2ay,-2az,0), pb, a2)  = a2 - 2*dot(a,b)
//   d2   = sdot4(pb, pb, dot1)                     = a2 + b2 - 2ab
// Scan key (d2<<7)|jl (jl = wave-uniform local index, SGPR) -> one
// v_lshl_add_u32. Branchless 9-op sorted-insert network. TWO independent
// insert streams per lane (even/odd k) for ILP through the serial chain.
// 512-thread blocks (8 rows) -> 4 blocks/CU by 32KB LDS -> 100% occupancy.

namespace {
constexpr int kB = 4;
constexpr int kNa = 8192;
constexpr int kNb = 8192;
constexpr int kC = 64;
constexpr int kWaves = 8;               // 8 waves/block, one output row per wave
constexpr int kThreads = kWaves * 64;   // 512
constexpr int kBlocksPerBatch = kNa / kWaves;  // 1024
}

__device__ __forceinline__ uint32_t umin_(uint32_t a, uint32_t b) { return a < b ? a : b; }
__device__ __forceinline__ uint32_t umax_(uint32_t a, uint32_t b) { return a > b ? a : b; }

// i-th smallest of the union of two sorted 5-lists (keep 5 smallest)
__device__ __forceinline__ void merge5_(uint32_t& t0, uint32_t& t1, uint32_t& t2,
                                        uint32_t& t3, uint32_t& t4,
                                        uint32_t b0, uint32_t b1, uint32_t b2,
                                        uint32_t b3, uint32_t b4) {
    const uint32_t c0 = umin_(t0, b0);
    const uint32_t c1 = umin_(umin_(umax_(t0, b0), t1), b1);
    const uint32_t c2 = umin_(umin_(umax_(t0, b1), umax_(t1, b0)), umin_(t2, b2));
    const uint32_t c3 = umin_(umin_(umax_(t0, b2), umax_(t1, b1)),
                              umin_(umax_(t2, b0), umin_(t3, b3)));
    const uint32_t c4 = umin_(umin_(umax_(t0, b3), umax_(t1, b2)),
                              umin_(umin_(umax_(t2, b1), umax_(t3, b0)),
                                    umin_(t4, b4)));
    t0 = c0; t1 = c1; t2 = c2; t3 = c3; t4 = c4;
}

#define INSERT5(T0, T1, T2, T3, T4, KEY) do {               \
    const uint32_t m0_ = umax_(T0, KEY); T0 = umin_(T0, KEY); \
    const uint32_t m1_ = umax_(T1, m0_); T1 = umin_(T1, m0_); \
    const uint32_t m2_ = umax_(T2, m1_); T2 = umin_(T2, m1_); \
    const uint32_t m3_ = umax_(T3, m2_); T3 = umin_(T3, m2_); \
    T4 = umin_(T4, m3_); } while (0)

__global__ __launch_bounds__(kThreads, 8)
void dist_match_kernel(const int* __restrict__ coords_a,
                       const int* __restrict__ coords_b,
                       const float* __restrict__ feat_a,
                       const float* __restrict__ feat_b,
                       float* __restrict__ out)
{
    __shared__ int spack[kNb];  // 32 KB: coords_b byte-packed x | y<<8 | z<<16

    const int b = blockIdx.x / kBlocksPerBatch;
    const int rowBase = (blockIdx.x % kBlocksPerBatch) * kWaves;
    const int tid = threadIdx.x;
    const int lane = tid & 63;
    const int wave = tid >> 6;

    // ---- stage byte-packed coords_b for this batch into LDS ----
    const int* cb = coords_b + (size_t)b * kNb * 3;
    for (int j = tid; j < kNb; j += kThreads) {
        const int x = cb[3 * j + 0];
        const int y = cb[3 * j + 1];
        const int z = cb[3 * j + 2];
        spack[j] = x | (y << 8) | (z << 16);
    }
    __syncthreads();

    const int row = rowBase + wave;
    const int* ca = coords_a + ((size_t)b * kNa + row) * 3;
    const int ax = ca[0], ay = ca[1], az = ca[2];
    const int a2 = ax * ax + ay * ay + az * az;
    const int paneg2 = ((-2 * ax) & 255) | (((-2 * ay) & 255) << 8)
                     | (((-2 * az) & 255) << 16);   // bytes: -2a as i8

    // ---- two independent branchless scan streams (even/odd k) ----
    uint32_t A0 = 0xFFFFFFFFu, A1 = A0, A2 = A0, A3 = A0, A4 = A0;
    uint32_t B0 = A0, B1 = A0, B2 = A0, B3 = A0, B4 = A0;

    #pragma unroll 2
    for (int k2 = 0; k2 < kNb / 512; ++k2) {         // 16 iters, 8 cands/lane
        const int baseA = (2 * k2) * 256 + lane * 4;
        const int4 pA = *reinterpret_cast<const int4*>(spack + baseA);
        const int4 pB = *reinterpret_cast<const int4*>(spack + baseA + 256);
        const int psA[4] = {pA.x, pA.y, pA.z, pA.w};
        const int psB[4] = {pB.x, pB.y, pB.z, pB.w};
        #pragma unroll
        for (int u = 0; u < 4; ++u) {
            const int pa_ = psA[u];
            const int dotA = __builtin_amdgcn_sdot4(paneg2, pa_, a2, false);
            const int d2A  = __builtin_amdgcn_sdot4(pa_, pa_, dotA, false);
            const uint32_t keyA = ((uint32_t)d2A << 7)
                                | (uint32_t)(4 * (2 * k2) + u);
            INSERT5(A0, A1, A2, A3, A4, keyA);

            const int pb_ = psB[u];
            const int dotB = __builtin_amdgcn_sdot4(paneg2, pb_, a2, false);
            const int d2B  = __builtin_amdgcn_sdot4(pb_, pb_, dotB, false);
            const uint32_t keyB = ((uint32_t)d2B << 7)
                                | (uint32_t)(4 * (2 * k2 + 1) + u);
            INSERT5(B0, B1, B2, B3, B4, keyB);
        }
    }

    // ---- in-lane merge of the two streams (scan-key order == full order) ----
    merge5_(A0, A1, A2, A3, A4, B0, B1, B2, B3, B4);

    // ---- rebuild full keys (d2<<13)|j ; j = (jl>>2)*256 + lane*4 + (jl&3) ----
    const uint32_t laneBits = (uint32_t)lane << 2;
    uint32_t t0, t1, t2, t3, t4;
    {
        uint32_t* src[5] = {&A0, &A1, &A2, &A3, &A4};
        uint32_t* dst[5] = {&t0, &t1, &t2, &t3, &t4};
        #pragma unroll
        for (int t = 0; t < 5; ++t) {
            const uint32_t key = *src[t];
            const uint32_t jl = key & 127u;
            const uint32_t d2 = key >> 7;
            *dst[t] = (d2 << 13) | ((jl >> 2) << 8) | laneBits | (jl & 3u);
        }
    }

    // ---- butterfly merge of sorted 5-lists across the 64 lanes ----
    #pragma unroll
    for (int s = 1; s < 64; s <<= 1) {
        const uint32_t b0 = (uint32_t)__shfl_xor((int)t0, s);
        const uint32_t b1 = (uint32_t)__shfl_xor((int)t1, s);
        const uint32_t b2 = (uint32_t)__shfl_xor((int)t2, s);
        const uint32_t b3 = (uint32_t)__shfl_xor((int)t3, s);
        const uint32_t b4 = (uint32_t)__shfl_xor((int)t4, s);
        merge5_(t0, t1, t2, t3, t4, b0, b1, b2, b3, b4);
    }
    // every lane now holds the global sorted top-5 for this row

    // ---- weights + gather: lane == channel ----
    const float* fb = feat_b + (size_t)b * kNb * kC;
    const uint32_t keys[5] = {t0, t1, t2, t3, t4};
    float acc = 0.0f;
    #pragma unroll
    for (int t = 0; t < 5; ++t) {
        const uint32_t key = keys[t];
        const int j = (int)(key & 8191u);
        const float dist = sqrtf((float)(key >> 13)) * (1.0f / 32.0f);
        const float w = 0.5f - fminf(dist, 0.5f);
        acc += w * fb[(size_t)j * kC + lane];         // coalesced 256B per row
    }

    const size_t orow = ((size_t)b * kNa + row) * (2 * kC);
    out[orow + lane] = feat_a[((size_t)b * kNa + row) * kC + lane];
    out[orow + kC + lane] = acc;
}

extern "C" void kernel_launch(void* const* d_in, const int* in_sizes, int n_in,
                              void* d_out, int out_size, void* d_ws, size_t ws_size,
                              hipStream_t stream) {
    const int* coords_a = (const int*)d_in[0];
    const int* coords_b = (const int*)d_in[1];
    const float* feat_a = (const float*)d_in[2];
    const float* feat_b = (const float*)d_in[3];
    float* out = (float*)d_out;

    const int grid = kB * kBlocksPerBatch;  // 4096 blocks x 512 threads
    dist_match_kernel<<<grid, kThreads, 0, stream>>>(coords_a, coords_b,
                                                     feat_a, feat_b, out);
}

// Round 5
// 49.399 us; speedup vs baseline: 3.4834x; 2.3997x over previous
//
#include <hip/hip_runtime.h>
#include <stdint.h>

// DistMatchLayer via spatial bucketing (round 5: exact running-global-top5).
// Coords are integer lattice points in [0,32)^3 -> a "cell" is one coordinate;
// all b-points in a cell share one exact integer d2 to a given a-point.
// Pipeline: memset -> histogram -> scan(3) -> scatter -> main.
// Main kernel (wave per row): iterate a d2-sorted constexpr offset table in
// 64-entry chunks. Per chunk: per-lane local top-5 (branchless network) ->
// butterfly merge (all lanes hold chunk top-5) -> merge into persistent
// global top-5 g. g4 is EXACTLY the 5th-best-so-far, so stop when the next
// chunk's min d2 exceeds g4>>13. Round-4 bug fixed: no per-lane persistent
// lists, so the (never-in-practice) brute fallback starts from fresh
// registers instead of double-inserting scanned candidates.

namespace {
constexpr int kB = 4;
constexpr int kNa = 8192;
constexpr int kNb = 8192;
constexpr int kC = 64;

constexpr int kRad = 8;                 // offsets |d| <= 8, d2 <= 64
constexpr int kDMax = 64;
constexpr int kGrid = 48;               // 32 + 2*8 padded grid
constexpr int kGrid2 = kGrid * kGrid;   // 2304
constexpr int kGrid3 = kGrid2 * kGrid;  // 110592
constexpr int kOff = kRad * kGrid2 + kRad * kGrid + kRad;  // 19208

constexpr int kTabCap = 4992;           // 78 chunks of 64 (ball(8) has 2109 cells)
constexpr int kChunks = kTabCap / 64;

// ws layout (u32 units)
constexpr size_t kCntOff  = 0;                      // [442368] counts->cursor
constexpr size_t kInfoOff = 442368;                 // [442368] (start<<16)|cnt
constexpr size_t kPIdxOff = 884736;                 // [32768]
constexpr size_t kBSumOff = 917504;                 // [1728]
constexpr size_t kWsBytes = (919232ull) * 4ull;     // 3,676,928 B

constexpr int kScanBlocks = kB * kGrid3 / 256;      // 1728
constexpr int kBlocksPerBatchScan = kGrid3 / 256;   // 432

struct Tab { uint32_t e[kTabCap]; uint32_t n; };
constexpr Tab buildTab() {
    Tab t{};
    int cnt[kDMax + 1] = {};
    for (int dx = -kRad; dx <= kRad; ++dx)
        for (int dy = -kRad; dy <= kRad; ++dy)
            for (int dz = -kRad; dz <= kRad; ++dz) {
                const int d2 = dx * dx + dy * dy + dz * dz;
                if (d2 <= kDMax) cnt[d2]++;
            }
    int pos[kDMax + 1] = {};
    int run = 0;
    for (int d = 0; d <= kDMax; ++d) { pos[d] = run; run += cnt[d]; }
    for (int dx = -kRad; dx <= kRad; ++dx)
        for (int dy = -kRad; dy <= kRad; ++dy)
            for (int dz = -kRad; dz <= kRad; ++dz) {
                const int d2 = dx * dx + dy * dy + dz * dz;
                if (d2 <= kDMax) {
                    const int sd = dx * kGrid2 + dy * kGrid + dz + kOff;
                    t.e[pos[d2]++] = ((uint32_t)d2 << 18) | (uint32_t)sd;
                }
            }
    t.n = (uint32_t)run;
    for (int i = run; i < kTabCap; ++i) t.e[i] = 0x7FFFFFFFu;  // sentinel
    return t;
}
__device__ constexpr Tab kTab = buildTab();   // ~20 KB .rodata
}  // namespace

__device__ __forceinline__ uint32_t umin_(uint32_t a, uint32_t b) { return a < b ? a : b; }
__device__ __forceinline__ uint32_t umax_(uint32_t a, uint32_t b) { return a > b ? a : b; }

#define INSERT5(T0, T1, T2, T3, T4, KEY) do {                 \
    const uint32_t m0_ = umax_(T0, KEY); T0 = umin_(T0, KEY); \
    const uint32_t m1_ = umax_(T1, m0_); T1 = umin_(T1, m0_); \
    const uint32_t m2_ = umax_(T2, m1_); T2 = umin_(T2, m1_); \
    const uint32_t m3_ = umax_(T3, m2_); T3 = umin_(T3, m2_); \
    T4 = umin_(T4, m3_); } while (0)

__device__ __forceinline__ void merge5_(uint32_t& t0, uint32_t& t1, uint32_t& t2,
                                        uint32_t& t3, uint32_t& t4,
                                        uint32_t b0, uint32_t b1, uint32_t b2,
                                        uint32_t b3, uint32_t b4) {
    const uint32_t c0 = umin_(t0, b0);
    const uint32_t c1 = umin_(umin_(umax_(t0, b0), t1), b1);
    const uint32_t c2 = umin_(umin_(umax_(t0, b1), umax_(t1, b0)), umin_(t2, b2));
    const uint32_t c3 = umin_(umin_(umax_(t0, b2), umax_(t1, b1)),
                              umin_(umax_(t2, b0), umin_(t3, b3)));
    const uint32_t c4 = umin_(umin_(umax_(t0, b3), umax_(t1, b2)),
                              umin_(umin_(umax_(t2, b1), umax_(t3, b0)),
                                    umin_(t4, b4)));
    t0 = c0; t1 = c1; t2 = c2; t3 = c3; t4 = c4;
}

// butterfly: after this, all 64 lanes hold the wave-global top-5 (sorted)
__device__ __forceinline__ void waveMerge5_(uint32_t& t0, uint32_t& t1, uint32_t& t2,
                                            uint32_t& t3, uint32_t& t4) {
    #pragma unroll
    for (int s = 1; s < 64; s <<= 1) {
        const uint32_t b0 = (uint32_t)__shfl_xor((int)t0, s);
        const uint32_t b1 = (uint32_t)__shfl_xor((int)t1, s);
        const uint32_t b2 = (uint32_t)__shfl_xor((int)t2, s);
        const uint32_t b3 = (uint32_t)__shfl_xor((int)t3, s);
        const uint32_t b4 = (uint32_t)__shfl_xor((int)t4, s);
        merge5_(t0, t1, t2, t3, t4, b0, b1, b2, b3, b4);
    }
}

// ---------------- setup kernels ----------------

__global__ void k_hist(const int* __restrict__ coords_b, uint32_t* __restrict__ cellCnt) {
    const int i = blockIdx.x * blockDim.x + threadIdx.x;
    if (i >= kB * kNb) return;
    const int b = i >> 13;
    const int* p = coords_b + (size_t)i * 3;
    const int cell = (p[0] + kRad) * kGrid2 + (p[1] + kRad) * kGrid + (p[2] + kRad);
    atomicAdd(&cellCnt[b * kGrid3 + cell], 1u);
}

__global__ void k_scan1(const uint32_t* __restrict__ cellCnt,
                        uint32_t* __restrict__ cellIncl,
                        uint32_t* __restrict__ blockSums) {
    __shared__ uint32_t s[256];
    const int g = blockIdx.x;
    const int t = threadIdx.x;
    const int idx = g * 256 + t;
    s[t] = cellCnt[idx];
    __syncthreads();
    for (int off = 1; off < 256; off <<= 1) {
        const uint32_t add = (t >= off) ? s[t - off] : 0;
        __syncthreads();
        s[t] += add;
        __syncthreads();
    }
    cellIncl[idx] = s[t];
    if (t == 255) blockSums[g] = s[255];
}

__global__ void k_scan2(uint32_t* __restrict__ blockSums) {  // 4 blocks x 512
    __shared__ uint32_t s[512];
    const int b = blockIdx.x;
    const int t = threadIdx.x;
    const uint32_t v = (t < kBlocksPerBatchScan) ? blockSums[b * kBlocksPerBatchScan + t] : 0;
    s[t] = v;
    __syncthreads();
    for (int off = 1; off < 512; off <<= 1) {
        const uint32_t add = (t >= off) ? s[t - off] : 0;
        __syncthreads();
        s[t] += add;
        __syncthreads();
    }
    if (t < kBlocksPerBatchScan) blockSums[b * kBlocksPerBatchScan + t] = s[t] - v;
}

__global__ void k_scan3(uint32_t* __restrict__ cellCnt,      // -> cursor (start)
                        uint32_t* __restrict__ cellInfo,     // incl -> (start<<16)|cnt
                        const uint32_t* __restrict__ blockSums) {
    const int g = blockIdx.x;
    const int t = threadIdx.x;
    const int idx = g * 256 + t;
    const uint32_t cnt  = cellCnt[idx];
    const uint32_t incl = cellInfo[idx];
    const uint32_t start = blockSums[g] + incl - cnt;  // exclusive within batch
    cellInfo[idx] = (start << 16) | cnt;
    cellCnt[idx]  = start;
}

__global__ void k_scatter(const int* __restrict__ coords_b,
                          uint32_t* __restrict__ cursor,
                          uint32_t* __restrict__ pointIdx) {
    const int i = blockIdx.x * blockDim.x + threadIdx.x;
    if (i >= kB * kNb) return;
    const int b = i >> 13;
    const int j = i & (kNb - 1);
    const int* p = coords_b + (size_t)i * 3;
    const int cell = (p[0] + kRad) * kGrid2 + (p[1] + kRad) * kGrid + (p[2] + kRad);
    const uint32_t pos = atomicAdd(&cursor[b * kGrid3 + cell], 1u);
    pointIdx[(size_t)b * kNb + pos] = (uint32_t)j;
}

// ---------------- main kernel: wave-per-row shell search ----------------

__global__ __launch_bounds__(512, 8)
void dist_match_bucket(const int* __restrict__ coords_a,
                       const int* __restrict__ coords_b,
                       const float* __restrict__ feat_a,
                       const float* __restrict__ feat_b,
                       const uint32_t* __restrict__ cellInfo,
                       const uint32_t* __restrict__ pointIdx,
                       float* __restrict__ out)
{
    const int b = blockIdx.x >> 10;                // 1024 blocks/batch
    const int rowBase = (blockIdx.x & 1023) * 8;
    const int lane = threadIdx.x & 63;
    const int wave = threadIdx.x >> 6;
    const int row = rowBase + wave;

    const int* ca = coords_a + ((size_t)b * kNa + row) * 3;
    const int ax = ca[0], ay = ca[1], az = ca[2];
    const int aCell = (ax + kRad) * kGrid2 + (ay + kRad) * kGrid + (az + kRad);
    const int base = b * kGrid3 + aCell - kOff;
    const uint32_t* pIdxB = pointIdx + (size_t)b * kNb;

    // persistent global top-5 (identical on all lanes; g4 == exact 5th best)
    uint32_t g0 = 0xFFFFFFFFu, g1 = g0, g2 = g0, g3 = g0, g4 = g0;

    for (int c = 0; c < kChunks; ++c) {
        const uint32_t cd2 = kTab.e[c * 64] >> 18;       // uniform (sorted table)
        if (cd2 > (g4 >> 13)) break;                     // provably can't improve
        const uint32_t e = kTab.e[c * 64 + lane];
        const uint32_t ed2 = e >> 18;
        uint32_t cnt = 0, start = 0;
        if (ed2 <= (uint32_t)kDMax) {                    // excludes sentinels
            const uint32_t info = cellInfo[base + (int)(e & 0x3FFFFu)];
            cnt = info & 0xFFFFu;
            start = info >> 16;
        }
        // fresh per-chunk local top-5
        uint32_t l0 = 0xFFFFFFFFu, l1 = l0, l2 = l0, l3 = l0, l4 = l0;
        const uint32_t keyBase = ed2 << 13;
        for (uint32_t m = 0;; ++m) {
            const bool act = m < cnt;
            if (!__any(act)) break;
            if (act) {
                const uint32_t key = keyBase | pIdxB[start + m];
                INSERT5(l0, l1, l2, l3, l4, key);
            }
        }
        if (__any(l0 != 0xFFFFFFFFu)) {                  // chunk non-empty
            waveMerge5_(l0, l1, l2, l3, l4);             // chunk-global top-5
            merge5_(g0, g1, g2, g3, g4, l0, l1, l2, l3, l4);
        }
    }

    if ((g4 >> 13) > (uint32_t)kDMax) {
        // < 5 points within d<=8 of this row (prob ~0). Exact brute rescan
        // from FRESH registers (round-4 bug: double-insert into populated list).
        const int* cb = coords_b + (size_t)b * kNb * 3;
        uint32_t t0 = 0xFFFFFFFFu, t1 = t0, t2 = t0, t3 = t0, t4 = t0;
        for (int j = lane; j < kNb; j += 64) {
            const int dx = ax - cb[3 * j + 0];
            const int dy = ay - cb[3 * j + 1];
            const int dz = az - cb[3 * j + 2];
            const uint32_t d2 = (uint32_t)(dx * dx + dy * dy + dz * dz);
            const uint32_t key = (d2 << 13) | (uint32_t)j;
            INSERT5(t0, t1, t2, t3, t4, key);
        }
        waveMerge5_(t0, t1, t2, t3, t4);
        g0 = t0; g1 = t1; g2 = t2; g3 = t3; g4 = t4;
    }

    // ---- weights + gather: lane == channel ----
    const float* fb = feat_b + (size_t)b * kNb * kC;
    const uint32_t keys[5] = {g0, g1, g2, g3, g4};
    float acc = 0.0f;
    #pragma unroll
    for (int t = 0; t < 5; ++t) {
        const uint32_t key = keys[t];
        const int j = (int)(key & 8191u);
        const float dist = sqrtf((float)(key >> 13)) * (1.0f / 32.0f);
        const float w = 0.5f - fminf(dist, 0.5f);
        acc += w * fb[(size_t)j * kC + lane];
    }

    const size_t orow = ((size_t)b * kNa + row) * (2 * kC);
    out[orow + lane] = feat_a[((size_t)b * kNa + row) * kC + lane];
    out[orow + kC + lane] = acc;
}

// ---------------- brute kernel (fallback if ws too small) ----------------

__global__ __launch_bounds__(512, 8)
void dist_match_brute(const int* __restrict__ coords_a,
                      const int* __restrict__ coords_b,
                      const float* __restrict__ feat_a,
                      const float* __restrict__ feat_b,
                      float* __restrict__ out)
{
    __shared__ int spack[kNb];
    const int b = blockIdx.x >> 10;
    const int rowBase = (blockIdx.x & 1023) * 8;
    const int tid = threadIdx.x;
    const int lane = tid & 63;
    const int wave = tid >> 6;

    const int* cb = coords_b + (size_t)b * kNb * 3;
    for (int j = tid; j < kNb; j += 512) {
        spack[j] = cb[3 * j + 0] | (cb[3 * j + 1] << 8) | (cb[3 * j + 2] << 16);
    }
    __syncthreads();

    const int row = rowBase + wave;
    const int* ca = coords_a + ((size_t)b * kNa + row) * 3;
    const int ax = ca[0], ay = ca[1], az = ca[2];
    const int a2 = ax * ax + ay * ay + az * az;
    const int paneg2 = ((-2 * ax) & 255) | (((-2 * ay) & 255) << 8)
                     | (((-2 * az) & 255) << 16);

    uint32_t t0 = 0xFFFFFFFFu, t1 = t0, t2 = t0, t3 = t0, t4 = t0;
    for (int k = 0; k < kNb / 256; ++k) {
        const int baseI = k * 256 + lane * 4;
        const int4 p4 = *reinterpret_cast<const int4*>(spack + baseI);
        const int ps[4] = {p4.x, p4.y, p4.z, p4.w};
        #pragma unroll
        for (int u = 0; u < 4; ++u) {
            const int p = ps[u];
            const int dot1 = __builtin_amdgcn_sdot4(paneg2, p, a2, false);
            const int d2 = __builtin_amdgcn_sdot4(p, p, dot1, false);
            const uint32_t key = ((uint32_t)d2 << 13) | (uint32_t)(baseI + u);
            INSERT5(t0, t1, t2, t3, t4, key);
        }
    }
    waveMerge5_(t0, t1, t2, t3, t4);
    const float* fb = feat_b + (size_t)b * kNb * kC;
    const uint32_t keys[5] = {t0, t1, t2, t3, t4};
    float acc = 0.0f;
    #pragma unroll
    for (int t = 0; t < 5; ++t) {
        const uint32_t key = keys[t];
        const int j = (int)(key & 8191u);
        const float dist = sqrtf((float)(key >> 13)) * (1.0f / 32.0f);
        const float w = 0.5f - fminf(dist, 0.5f);
        acc += w * fb[(size_t)j * kC + lane];
    }
    const size_t orow = ((size_t)b * kNa + row) * (2 * kC);
    out[orow + lane] = feat_a[((size_t)b * kNa + row) * kC + lane];
    out[orow + kC + lane] = acc;
}

extern "C" void kernel_launch(void* const* d_in, const int* in_sizes, int n_in,
                              void* d_out, int out_size, void* d_ws, size_t ws_size,
                              hipStream_t stream) {
    const int* coords_a = (const int*)d_in[0];
    const int* coords_b = (const int*)d_in[1];
    const float* feat_a = (const float*)d_in[2];
    const float* feat_b = (const float*)d_in[3];
    float* out = (float*)d_out;

    if (ws_size < kWsBytes) {
        dist_match_brute<<<kB * 1024, 512, 0, stream>>>(coords_a, coords_b,
                                                        feat_a, feat_b, out);
        return;
    }

    uint32_t* ws32 = (uint32_t*)d_ws;
    uint32_t* cellCnt  = ws32 + kCntOff;   // counts -> cursor(start)
    uint32_t* cellInfo = ws32 + kInfoOff;  // incl scan -> (start<<16)|cnt
    uint32_t* pointIdx = ws32 + kPIdxOff;
    uint32_t* blockSums = ws32 + kBSumOff;

    hipMemsetAsync(cellCnt, 0, (size_t)kB * kGrid3 * 4, stream);
    k_hist<<<kB * kNb / 256, 256, 0, stream>>>(coords_b, cellCnt);
    k_scan1<<<kScanBlocks, 256, 0, stream>>>(cellCnt, cellInfo, blockSums);
    k_scan2<<<kB, 512, 0, stream>>>(blockSums);
    k_scan3<<<kScanBlocks, 256, 0, stream>>>(cellCnt, cellInfo, blockSums);
    k_scatter<<<kB * kNb / 256, 256, 0, stream>>>(coords_b, cellCnt, pointIdx);
    dist_match_bucket<<<kB * 1024, 512, 0, stream>>>(coords_a, coords_b,
                                                     feat_a, feat_b,
                                                     cellInfo, pointIdx, out);
}

// Round 6
// 40.979 us; speedup vs baseline: 4.1991x; 1.2055x over previous
//
#include <hip/hip_runtime.h>
#include <stdint.h>

// DistMatchLayer via spatial bucketing, round 6: direct-mapped slot table.
// Coords are integer lattice points in [0,32)^3 -> a cell is one coordinate;
// all b-points in a cell share one exact integer d2 to a given a-point.
//
// Pipeline (3 dispatches): memset(cnt+ovfCnt) -> scatter -> main.
//   scatter: pos = atomicAdd(cnt[cell]); pos<8 -> slots[cell*8+pos]=j,
//            else append j to per-batch overflow list (exactness preserved).
// Main (wave per row): iterate the d2-sorted constexpr offset table in
// MACRO-chunks of 128 entries (2 per lane). Per chunk: predicated int4 slot
// gathers, branchless insert of up to 2x4 (+rare 2x4 more) keys (d2<<13)|j
// into a fresh local top-5, one butterfly merge -> merge into persistent
// global top-5 g (g4 == exact 5th-best-so-far among scanned slot points).
// Stop when next chunk's min d2 > g4>>13 (strict: equal d2 could still win
// ties on j). Then fold in overflow points; if still <5 within d<=8 (prob~0)
// exact brute rescan from fresh registers. Stability: keys carry full j, and
// top-5-of-union is order-independent -> jax.lax.top_k tie order is exact.

namespace {
constexpr int kB = 4;
constexpr int kNa = 8192;
constexpr int kNb = 8192;
constexpr int kC = 64;

constexpr int kRad = 8;                 // offsets |d| <= 8, d2 <= 64
constexpr int kDMax = 64;
constexpr int kGrid = 48;               // 32 + 2*8 padded grid
constexpr int kGrid2 = kGrid * kGrid;   // 2304
constexpr int kGrid3 = kGrid2 * kGrid;  // 110592
constexpr int kOff = kRad * kGrid2 + kRad * kGrid + kRad;  // 19208

constexpr int kTabCap = 4992;           // 39 macro-chunks of 128 (ball(8)=2109)
constexpr int kMacro = kTabCap / 128;   // 39

constexpr int kSlotK = 8;
constexpr int kOvfCap = 256;

// ws layout (u32 units)
constexpr size_t kCntOff  = 0;                            // [442368]
constexpr size_t kOvfCntOff = 442368;                     // [4]
constexpr size_t kOvfIdxOff = 442372;                     // [4*256]
constexpr size_t kSlotOff = 443396;                       // 16B-aligned (x4)
constexpr size_t kSlotWords = (size_t)kB * kGrid3 * kSlotK;  // 3,538,944
constexpr size_t kWsWords = kSlotOff + kSlotWords;        // 3,982,340
constexpr size_t kWsBytes = kWsWords * 4ull;              // ~15.9 MB
constexpr size_t kClrBytes = (kOvfCntOff + 4) * 4ull;     // cnt + ovfCnt

struct Tab { uint32_t e[kTabCap]; uint32_t n; };
constexpr Tab buildTab() {
    Tab t{};
    int cnt[kDMax + 1] = {};
    for (int dx = -kRad; dx <= kRad; ++dx)
        for (int dy = -kRad; dy <= kRad; ++dy)
            for (int dz = -kRad; dz <= kRad; ++dz) {
                const int d2 = dx * dx + dy * dy + dz * dz;
                if (d2 <= kDMax) cnt[d2]++;
            }
    int pos[kDMax + 1] = {};
    int run = 0;
    for (int d = 0; d <= kDMax; ++d) { pos[d] = run; run += cnt[d]; }
    for (int dx = -kRad; dx <= kRad; ++dx)
        for (int dy = -kRad; dy <= kRad; ++dy)
            for (int dz = -kRad; dz <= kRad; ++dz) {
                const int d2 = dx * dx + dy * dy + dz * dz;
                if (d2 <= kDMax) {
                    const int sd = dx * kGrid2 + dy * kGrid + dz + kOff;
                    t.e[pos[d2]++] = ((uint32_t)d2 << 18) | (uint32_t)sd;
                }
            }
    t.n = (uint32_t)run;
    for (int i = run; i < kTabCap; ++i) t.e[i] = 0x7FFFFFFFu;  // sentinel
    return t;
}
__device__ constexpr Tab kTab = buildTab();   // ~20 KB .rodata
}  // namespace

__device__ __forceinline__ uint32_t umin_(uint32_t a, uint32_t b) { return a < b ? a : b; }
__device__ __forceinline__ uint32_t umax_(uint32_t a, uint32_t b) { return a > b ? a : b; }

#define INSERT5(T0, T1, T2, T3, T4, KEY) do {                 \
    const uint32_t m0_ = umax_(T0, KEY); T0 = umin_(T0, KEY); \
    const uint32_t m1_ = umax_(T1, m0_); T1 = umin_(T1, m0_); \
    const uint32_t m2_ = umax_(T2, m1_); T2 = umin_(T2, m1_); \
    const uint32_t m3_ = umax_(T3, m2_); T3 = umin_(T3, m2_); \
    T4 = umin_(T4, m3_); } while (0)

__device__ __forceinline__ void merge5_(uint32_t& t0, uint32_t& t1, uint32_t& t2,
                                        uint32_t& t3, uint32_t& t4,
                                        uint32_t b0, uint32_t b1, uint32_t b2,
                                        uint32_t b3, uint32_t b4) {
    const uint32_t c0 = umin_(t0, b0);
    const uint32_t c1 = umin_(umin_(umax_(t0, b0), t1), b1);
    const uint32_t c2 = umin_(umin_(umax_(t0, b1), umax_(t1, b0)), umin_(t2, b2));
    const uint32_t c3 = umin_(umin_(umax_(t0, b2), umax_(t1, b1)),
                              umin_(umax_(t2, b0), umin_(t3, b3)));
    const uint32_t c4 = umin_(umin_(umax_(t0, b3), umax_(t1, b2)),
                              umin_(umin_(umax_(t2, b1), umax_(t3, b0)),
                                    umin_(t4, b4)));
    t0 = c0; t1 = c1; t2 = c2; t3 = c3; t4 = c4;
}

// butterfly: after this, all 64 lanes hold the wave-global sorted top-5
__device__ __forceinline__ void waveMerge5_(uint32_t& t0, uint32_t& t1, uint32_t& t2,
                                            uint32_t& t3, uint32_t& t4) {
    #pragma unroll
    for (int s = 1; s < 64; s <<= 1) {
        const uint32_t b0 = (uint32_t)__shfl_xor((int)t0, s);
        const uint32_t b1 = (uint32_t)__shfl_xor((int)t1, s);
        const uint32_t b2 = (uint32_t)__shfl_xor((int)t2, s);
        const uint32_t b3 = (uint32_t)__shfl_xor((int)t3, s);
        const uint32_t b4 = (uint32_t)__shfl_xor((int)t4, s);
        merge5_(t0, t1, t2, t3, t4, b0, b1, b2, b3, b4);
    }
}

// ---------------- scatter (the only setup kernel) ----------------

__global__ void k_scatter(const int* __restrict__ coords_b,
                          uint32_t* __restrict__ cnt,
                          uint32_t* __restrict__ slots,
                          uint32_t* __restrict__ ovfCnt,
                          uint32_t* __restrict__ ovfIdx) {
    const int i = blockIdx.x * blockDim.x + threadIdx.x;
    if (i >= kB * kNb) return;
    const int b = i >> 13;
    const int j = i & (kNb - 1);
    const int* p = coords_b + (size_t)i * 3;
    const int cell = b * kGrid3
                   + (p[0] + kRad) * kGrid2 + (p[1] + kRad) * kGrid + (p[2] + kRad);
    const uint32_t pos = atomicAdd(&cnt[cell], 1u);
    if (pos < (uint32_t)kSlotK) {
        slots[(size_t)cell * kSlotK + pos] = (uint32_t)j;
    } else {
        const uint32_t op = atomicAdd(&ovfCnt[b], 1u);
        if (op < (uint32_t)kOvfCap) ovfIdx[b * kOvfCap + op] = (uint32_t)j;
    }
}

// ---------------- main kernel: wave-per-row shell search ----------------

__global__ __launch_bounds__(512, 8)
void dist_match_bucket(const int* __restrict__ coords_a,
                       const int* __restrict__ coords_b,
                       const float* __restrict__ feat_a,
                       const float* __restrict__ feat_b,
                       const uint32_t* __restrict__ cnt,
                       const uint32_t* __restrict__ slots,
                       const uint32_t* __restrict__ ovfCnt,
                       const uint32_t* __restrict__ ovfIdx,
                       float* __restrict__ out)
{
    const int b = blockIdx.x >> 10;                // 1024 blocks/batch
    const int rowBase = (blockIdx.x & 1023) * 8;
    const int lane = threadIdx.x & 63;
    const int wave = threadIdx.x >> 6;
    const int row = rowBase + wave;

    const int* ca = coords_a + ((size_t)b * kNa + row) * 3;
    const int ax = ca[0], ay = ca[1], az = ca[2];
    const int aCell = (ax + kRad) * kGrid2 + (ay + kRad) * kGrid + (az + kRad);
    const int base = b * kGrid3 + aCell - kOff;

    // persistent global top-5 (same on all lanes; g4 == exact 5th-best-so-far)
    uint32_t g0 = 0xFFFFFFFFu, g1 = g0, g2 = g0, g3 = g0, g4 = g0;

    for (int c = 0; c < kMacro; ++c) {
        const uint32_t cd2 = kTab.e[c * 128] >> 18;      // uniform (sorted)
        if (cd2 > (g4 >> 13)) break;                     // strict: ties on j live
        const uint32_t e0 = kTab.e[c * 128 + lane];
        const uint32_t e1 = kTab.e[c * 128 + 64 + lane];
        const uint32_t d20 = e0 >> 18, d21 = e1 >> 18;
        const int cell0 = base + (int)(e0 & 0x3FFFFu);
        const int cell1 = base + (int)(e1 & 0x3FFFFu);
        uint32_t n0 = 0, n1 = 0;
        if (d20 <= (uint32_t)kDMax) n0 = umin_(cnt[cell0], (uint32_t)kSlotK);
        if (d21 <= (uint32_t)kDMax) n1 = umin_(cnt[cell1], (uint32_t)kSlotK);

        if (__any((n0 | n1) != 0)) {
            uint32_t l0 = 0xFFFFFFFFu, l1 = l0, l2 = l0, l3 = l0, l4 = l0;
            const uint32_t kb0 = d20 << 13, kb1 = d21 << 13;
            uint4 s0, s1;
            if (n0) s0 = *reinterpret_cast<const uint4*>(slots + (size_t)cell0 * kSlotK);
            if (n1) s1 = *reinterpret_cast<const uint4*>(slots + (size_t)cell1 * kSlotK);
            #define SLOT_INS(W, N, KB, M) do {                                   \
                const uint32_t kk_ = ((M) < (N)) ? ((KB) | (W)) : 0xFFFFFFFFu;   \
                INSERT5(l0, l1, l2, l3, l4, kk_); } while (0)
            if (n0) {
                SLOT_INS(s0.x, n0, kb0, 0u); SLOT_INS(s0.y, n0, kb0, 1u);
                SLOT_INS(s0.z, n0, kb0, 2u); SLOT_INS(s0.w, n0, kb0, 3u);
            }
            if (n1) {
                SLOT_INS(s1.x, n1, kb1, 0u); SLOT_INS(s1.y, n1, kb1, 1u);
                SLOT_INS(s1.z, n1, kb1, 2u); SLOT_INS(s1.w, n1, kb1, 3u);
            }
            if (__any((n0 > 4u) | (n1 > 4u))) {          // essentially never
                #pragma unroll
                for (uint32_t m = 4; m < 8; ++m) {
                    if (m < n0) {
                        const uint32_t kk = kb0 | slots[(size_t)cell0 * kSlotK + m];
                        INSERT5(l0, l1, l2, l3, l4, kk);
                    }
                    if (m < n1) {
                        const uint32_t kk = kb1 | slots[(size_t)cell1 * kSlotK + m];
                        INSERT5(l0, l1, l2, l3, l4, kk);
                    }
                }
            }
            #undef SLOT_INS
            waveMerge5_(l0, l1, l2, l3, l4);             // chunk-global top-5
            merge5_(g0, g1, g2, g3, g4, l0, l1, l2, l3, l4);
        }
    }

    // ---- fold in overflow points (cells that spilled past 8 slots) ----
    const uint32_t ovf = ovfCnt[b];
    if (ovf > (uint32_t)kOvfCap) {
        // unreachable in practice; exact full rescan
        const int* cb = coords_b + (size_t)b * kNb * 3;
        uint32_t t0 = 0xFFFFFFFFu, t1 = t0, t2 = t0, t3 = t0, t4 = t0;
        for (int j = lane; j < kNb; j += 64) {
            const int dx = ax - cb[3 * j + 0];
            const int dy = ay - cb[3 * j + 1];
            const int dz = az - cb[3 * j + 2];
            const uint32_t d2 = (uint32_t)(dx * dx + dy * dy + dz * dz);
            INSERT5(t0, t1, t2, t3, t4, (d2 << 13) | (uint32_t)j);
        }
        waveMerge5_(t0, t1, t2, t3, t4);
        g0 = t0; g1 = t1; g2 = t2; g3 = t3; g4 = t4;
    } else {
        if (ovf > 0) {
            const int* cb = coords_b + (size_t)b * kNb * 3;
            uint32_t l0 = 0xFFFFFFFFu, l1 = l0, l2 = l0, l3 = l0, l4 = l0;
            for (uint32_t i = (uint32_t)lane; i < ovf; i += 64) {
                const uint32_t j = ovfIdx[b * kOvfCap + i];
                const int dx = ax - cb[3 * j + 0];
                const int dy = ay - cb[3 * j + 1];
                const int dz = az - cb[3 * j + 2];
                const uint32_t d2 = (uint32_t)(dx * dx + dy * dy + dz * dz);
                INSERT5(l0, l1, l2, l3, l4, (d2 << 13) | j);
            }
            waveMerge5_(l0, l1, l2, l3, l4);
            merge5_(g0, g1, g2, g3, g4, l0, l1, l2, l3, l4);
        }
        if ((g4 >> 13) > (uint32_t)kDMax) {
            // < 5 points within d<=8 of this row (prob ~0): exact rescan
            const int* cb = coords_b + (size_t)b * kNb * 3;
            uint32_t t0 = 0xFFFFFFFFu, t1 = t0, t2 = t0, t3 = t0, t4 = t0;
            for (int j = lane; j < kNb; j += 64) {
                const int dx = ax - cb[3 * j + 0];
                const int dy = ay - cb[3 * j + 1];
                const int dz = az - cb[3 * j + 2];
                const uint32_t d2 = (uint32_t)(dx * dx + dy * dy + dz * dz);
                INSERT5(t0, t1, t2, t3, t4, (d2 << 13) | (uint32_t)j);
            }
            waveMerge5_(t0, t1, t2, t3, t4);
            g0 = t0; g1 = t1; g2 = t2; g3 = t3; g4 = t4;
        }
    }

    // ---- weights + gather: lane == channel ----
    const float* fb = feat_b + (size_t)b * kNb * kC;
    const uint32_t keys[5] = {g0, g1, g2, g3, g4};
    float acc = 0.0f;
    #pragma unroll
    for (int t = 0; t < 5; ++t) {
        const uint32_t key = keys[t];
        const int j = (int)(key & 8191u);
        const float dist = sqrtf((float)(key >> 13)) * (1.0f / 32.0f);
        const float w = 0.5f - fminf(dist, 0.5f);
        acc += w * fb[(size_t)j * kC + lane];             // coalesced 256B/row
    }

    const size_t orow = ((size_t)b * kNa + row) * (2 * kC);
    out[orow + lane] = feat_a[((size_t)b * kNa + row) * kC + lane];
    out[orow + kC + lane] = acc;
}

// ---------------- brute kernel (fallback if ws too small) ----------------

__global__ __launch_bounds__(512, 8)
void dist_match_brute(const int* __restrict__ coords_a,
                      const int* __restrict__ coords_b,
                      const float* __restrict__ feat_a,
                      const float* __restrict__ feat_b,
                      float* __restrict__ out)
{
    __shared__ int spack[kNb];
    const int b = blockIdx.x >> 10;
    const int rowBase = (blockIdx.x & 1023) * 8;
    const int tid = threadIdx.x;
    const int lane = tid & 63;
    const int wave = tid >> 6;

    const int* cb = coords_b + (size_t)b * kNb * 3;
    for (int j = tid; j < kNb; j += 512) {
        spack[j] = cb[3 * j + 0] | (cb[3 * j + 1] << 8) | (cb[3 * j + 2] << 16);
    }
    __syncthreads();

    const int row = rowBase + wave;
    const int* ca = coords_a + ((size_t)b * kNa + row) * 3;
    const int ax = ca[0], ay = ca[1], az = ca[2];
    const int a2 = ax * ax + ay * ay + az * az;
    const int paneg2 = ((-2 * ax) & 255) | (((-2 * ay) & 255) << 8)
                     | (((-2 * az) & 255) << 16);

    uint32_t t0 = 0xFFFFFFFFu, t1 = t0, t2 = t0, t3 = t0, t4 = t0;
    for (int k = 0; k < kNb / 256; ++k) {
        const int baseI = k * 256 + lane * 4;
        const int4 p4 = *reinterpret_cast<const int4*>(spack + baseI);
        const int ps[4] = {p4.x, p4.y, p4.z, p4.w};
        #pragma unroll
        for (int u = 0; u < 4; ++u) {
            const int p = ps[u];
            const int dot1 = __builtin_amdgcn_sdot4(paneg2, p, a2, false);
            const int d2 = __builtin_amdgcn_sdot4(p, p, dot1, false);
            const uint32_t key = ((uint32_t)d2 << 13) | (uint32_t)(baseI + u);
            INSERT5(t0, t1, t2, t3, t4, key);
        }
    }
    waveMerge5_(t0, t1, t2, t3, t4);
    const float* fb = feat_b + (size_t)b * kNb * kC;
    const uint32_t keys[5] = {t0, t1, t2, t3, t4};
    float acc = 0.0f;
    #pragma unroll
    for (int t = 0; t < 5; ++t) {
        const uint32_t key = keys[t];
        const int j = (int)(key & 8191u);
        const float dist = sqrtf((float)(key >> 13)) * (1.0f / 32.0f);
        const float w = 0.5f - fminf(dist, 0.5f);
        acc += w * fb[(size_t)j * kC + lane];
    }
    const size_t orow = ((size_t)b * kNa + row) * (2 * kC);
    out[orow + lane] = feat_a[((size_t)b * kNa + row) * kC + lane];
    out[orow + kC + lane] = acc;
}

extern "C" void kernel_launch(void* const* d_in, const int* in_sizes, int n_in,
                              void* d_out, int out_size, void* d_ws, size_t ws_size,
                              hipStream_t stream) {
    const int* coords_a = (const int*)d_in[0];
    const int* coords_b = (const int*)d_in[1];
    const float* feat_a = (const float*)d_in[2];
    const float* feat_b = (const float*)d_in[3];
    float* out = (float*)d_out;

    if (ws_size < kWsBytes) {
        dist_match_brute<<<kB * 1024, 512, 0, stream>>>(coords_a, coords_b,
                                                        feat_a, feat_b, out);
        return;
    }

    uint32_t* ws32 = (uint32_t*)d_ws;
    uint32_t* cnt    = ws32 + kCntOff;
    uint32_t* ovfCnt = ws32 + kOvfCntOff;
    uint32_t* ovfIdx = ws32 + kOvfIdxOff;
    uint32_t* slots  = ws32 + kSlotOff;

    hipMemsetAsync(cnt, 0, kClrBytes, stream);           // cnt + ovfCnt
    k_scatter<<<kB * kNb / 256, 256, 0, stream>>>(coords_b, cnt, slots,
                                                  ovfCnt, ovfIdx);
    dist_match_bucket<<<kB * 1024, 512, 0, stream>>>(coords_a, coords_b,
                                                     feat_a, feat_b,
                                                     cnt, slots, ovfCnt, ovfIdx,
                                                     out);
}

// Round 7
// 40.595 us; speedup vs baseline: 4.2389x; 1.0095x over previous
//
#include <hip/hip_runtime.h>
#include <stdint.h>

// DistMatchLayer via spatial bucketing, round 7: custom clear kernel.
// Round-6 profile: hipMemsetAsync(1.77MB) ran via rocclr fillBufferAligned at
// 40 GB/s (~43 us) -- the pipeline's long pole. Replaced with a one-store-per
// -thread uint4 clear kernel. Scatter + main unchanged from round 6 (passing,
// absmax 0.0078125).
//
// Pipeline (3 dispatches): k_clear(cnt+ovfCnt) -> k_scatter -> main.
// Main (wave per row): iterate the d2-sorted constexpr offset table in
// macro-chunks of 128 entries (2/lane; chunk 0 covers all cells d2<=9, which
// almost always contains the true top-5 -> typically ONE butterfly per row).
// Exact: running global top-5 with full keys (d2<<13)|j; stop when next
// chunk's min d2 > g4>>13; overflow list + brute fallback keep it exact in
// all cases; key carries j so jax.lax.top_k stable tie order is reproduced.

namespace {
constexpr int kB = 4;
constexpr int kNa = 8192;
constexpr int kNb = 8192;
constexpr int kC = 64;

constexpr int kRad = 8;                 // offsets |d| <= 8, d2 <= 64
constexpr int kDMax = 64;
constexpr int kGrid = 48;               // 32 + 2*8 padded grid
constexpr int kGrid2 = kGrid * kGrid;   // 2304
constexpr int kGrid3 = kGrid2 * kGrid;  // 110592
constexpr int kOff = kRad * kGrid2 + kRad * kGrid + kRad;  // 19208

constexpr int kTabCap = 4992;           // 39 macro-chunks of 128 (ball(8)=2109)
constexpr int kMacro = kTabCap / 128;   // 39

constexpr int kSlotK = 8;
constexpr int kOvfCap = 256;

// ws layout (u32 units)
constexpr size_t kCntOff  = 0;                            // [442368]
constexpr size_t kOvfCntOff = 442368;                     // [4]
constexpr size_t kOvfIdxOff = 442372;                     // [4*256]
constexpr size_t kSlotOff = 443396;                       // 16B-aligned (x4)
constexpr size_t kSlotWords = (size_t)kB * kGrid3 * kSlotK;  // 3,538,944
constexpr size_t kWsWords = kSlotOff + kSlotWords;        // 3,982,340
constexpr size_t kWsBytes = kWsWords * 4ull;              // ~15.9 MB

constexpr size_t kClrWords = kOvfCntOff + kB;             // 442372 (cnt+ovfCnt)
constexpr int kClrVec = (int)(kClrWords / 4);             // 110593 uint4 stores
constexpr int kClrBlocks = (kClrVec + 255) / 256;         // 433

struct Tab { uint32_t e[kTabCap]; uint32_t n; };
constexpr Tab buildTab() {
    Tab t{};
    int cnt[kDMax + 1] = {};
    for (int dx = -kRad; dx <= kRad; ++dx)
        for (int dy = -kRad; dy <= kRad; ++dy)
            for (int dz = -kRad; dz <= kRad; ++dz) {
                const int d2 = dx * dx + dy * dy + dz * dz;
                if (d2 <= kDMax) cnt[d2]++;
            }
    int pos[kDMax + 1] = {};
    int run = 0;
    for (int d = 0; d <= kDMax; ++d) { pos[d] = run; run += cnt[d]; }
    for (int dx = -kRad; dx <= kRad; ++dx)
        for (int dy = -kRad; dy <= kRad; ++dy)
            for (int dz = -kRad; dz <= kRad; ++dz) {
                const int d2 = dx * dx + dy * dy + dz * dz;
                if (d2 <= kDMax) {
                    const int sd = dx * kGrid2 + dy * kGrid + dz + kOff;
                    t.e[pos[d2]++] = ((uint32_t)d2 << 18) | (uint32_t)sd;
                }
            }
    t.n = (uint32_t)run;
    for (int i = run; i < kTabCap; ++i) t.e[i] = 0x7FFFFFFFu;  // sentinel
    return t;
}
__device__ constexpr Tab kTab = buildTab();   // ~20 KB .rodata
}  // namespace

__device__ __forceinline__ uint32_t umin_(uint32_t a, uint32_t b) { return a < b ? a : b; }
__device__ __forceinline__ uint32_t umax_(uint32_t a, uint32_t b) { return a > b ? a : b; }

#define INSERT5(T0, T1, T2, T3, T4, KEY) do {                 \
    const uint32_t m0_ = umax_(T0, KEY); T0 = umin_(T0, KEY); \
    const uint32_t m1_ = umax_(T1, m0_); T1 = umin_(T1, m0_); \
    const uint32_t m2_ = umax_(T2, m1_); T2 = umin_(T2, m1_); \
    const uint32_t m3_ = umax_(T3, m2_); T3 = umin_(T3, m2_); \
    T4 = umin_(T4, m3_); } while (0)

__device__ __forceinline__ void merge5_(uint32_t& t0, uint32_t& t1, uint32_t& t2,
                                        uint32_t& t3, uint32_t& t4,
                                        uint32_t b0, uint32_t b1, uint32_t b2,
                                        uint32_t b3, uint32_t b4) {
    const uint32_t c0 = umin_(t0, b0);
    const uint32_t c1 = umin_(umin_(umax_(t0, b0), t1), b1);
    const uint32_t c2 = umin_(umin_(umax_(t0, b1), umax_(t1, b0)), umin_(t2, b2));
    const uint32_t c3 = umin_(umin_(umax_(t0, b2), umax_(t1, b1)),
                              umin_(umax_(t2, b0), umin_(t3, b3)));
    const uint32_t c4 = umin_(umin_(umax_(t0, b3), umax_(t1, b2)),
                              umin_(umin_(umax_(t2, b1), umax_(t3, b0)),
                                    umin_(t4, b4)));
    t0 = c0; t1 = c1; t2 = c2; t3 = c3; t4 = c4;
}

// butterfly: after this, all 64 lanes hold the wave-global sorted top-5
__device__ __forceinline__ void waveMerge5_(uint32_t& t0, uint32_t& t1, uint32_t& t2,
                                            uint32_t& t3, uint32_t& t4) {
    #pragma unroll
    for (int s = 1; s < 64; s <<= 1) {
        const uint32_t b0 = (uint32_t)__shfl_xor((int)t0, s);
        const uint32_t b1 = (uint32_t)__shfl_xor((int)t1, s);
        const uint32_t b2 = (uint32_t)__shfl_xor((int)t2, s);
        const uint32_t b3 = (uint32_t)__shfl_xor((int)t3, s);
        const uint32_t b4 = (uint32_t)__shfl_xor((int)t4, s);
        merge5_(t0, t1, t2, t3, t4, b0, b1, b2, b3, b4);
    }
}

// ---------------- clear + scatter ----------------

__global__ __launch_bounds__(256)
void k_clear(uint4* __restrict__ ws) {
    const int i = blockIdx.x * 256 + threadIdx.x;
    if (i < kClrVec) ws[i] = uint4{0u, 0u, 0u, 0u};
}

__global__ void k_scatter(const int* __restrict__ coords_b,
                          uint32_t* __restrict__ cnt,
                          uint32_t* __restrict__ slots,
                          uint32_t* __restrict__ ovfCnt,
                          uint32_t* __restrict__ ovfIdx) {
    const int i = blockIdx.x * blockDim.x + threadIdx.x;
    if (i >= kB * kNb) return;
    const int b = i >> 13;
    const int j = i & (kNb - 1);
    const int* p = coords_b + (size_t)i * 3;
    const int cell = b * kGrid3
                   + (p[0] + kRad) * kGrid2 + (p[1] + kRad) * kGrid + (p[2] + kRad);
    const uint32_t pos = atomicAdd(&cnt[cell], 1u);
    if (pos < (uint32_t)kSlotK) {
        slots[(size_t)cell * kSlotK + pos] = (uint32_t)j;
    } else {
        const uint32_t op = atomicAdd(&ovfCnt[b], 1u);
        if (op < (uint32_t)kOvfCap) ovfIdx[b * kOvfCap + op] = (uint32_t)j;
    }
}

// ---------------- main kernel: wave-per-row shell search ----------------

__global__ __launch_bounds__(512, 8)
void dist_match_bucket(const int* __restrict__ coords_a,
                       const int* __restrict__ coords_b,
                       const float* __restrict__ feat_a,
                       const float* __restrict__ feat_b,
                       const uint32_t* __restrict__ cnt,
                       const uint32_t* __restrict__ slots,
                       const uint32_t* __restrict__ ovfCnt,
                       const uint32_t* __restrict__ ovfIdx,
                       float* __restrict__ out)
{
    const int b = blockIdx.x >> 10;                // 1024 blocks/batch
    const int rowBase = (blockIdx.x & 1023) * 8;
    const int lane = threadIdx.x & 63;
    const int wave = threadIdx.x >> 6;
    const int row = rowBase + wave;

    const int* ca = coords_a + ((size_t)b * kNa + row) * 3;
    const int ax = ca[0], ay = ca[1], az = ca[2];
    const int aCell = (ax + kRad) * kGrid2 + (ay + kRad) * kGrid + (az + kRad);
    const int base = b * kGrid3 + aCell - kOff;

    // persistent global top-5 (same on all lanes; g4 == exact 5th-best-so-far)
    uint32_t g0 = 0xFFFFFFFFu, g1 = g0, g2 = g0, g3 = g0, g4 = g0;

    for (int c = 0; c < kMacro; ++c) {
        const uint32_t cd2 = kTab.e[c * 128] >> 18;      // uniform (sorted)
        if (cd2 > (g4 >> 13)) break;                     // strict: ties on j live
        const uint32_t e0 = kTab.e[c * 128 + lane];
        const uint32_t e1 = kTab.e[c * 128 + 64 + lane];
        const uint32_t d20 = e0 >> 18, d21 = e1 >> 18;
        const int cell0 = base + (int)(e0 & 0x3FFFFu);
        const int cell1 = base + (int)(e1 & 0x3FFFFu);
        uint32_t n0 = 0, n1 = 0;
        if (d20 <= (uint32_t)kDMax) n0 = umin_(cnt[cell0], (uint32_t)kSlotK);
        if (d21 <= (uint32_t)kDMax) n1 = umin_(cnt[cell1], (uint32_t)kSlotK);

        if (__any((n0 | n1) != 0)) {
            uint32_t l0 = 0xFFFFFFFFu, l1 = l0, l2 = l0, l3 = l0, l4 = l0;
            const uint32_t kb0 = d20 << 13, kb1 = d21 << 13;
            uint4 s0, s1;
            if (n0) s0 = *reinterpret_cast<const uint4*>(slots + (size_t)cell0 * kSlotK);
            if (n1) s1 = *reinterpret_cast<const uint4*>(slots + (size_t)cell1 * kSlotK);
            #define SLOT_INS(W, N, KB, M) do {                                   \
                const uint32_t kk_ = ((M) < (N)) ? ((KB) | (W)) : 0xFFFFFFFFu;   \
                INSERT5(l0, l1, l2, l3, l4, kk_); } while (0)
            if (n0) {
                SLOT_INS(s0.x, n0, kb0, 0u); SLOT_INS(s0.y, n0, kb0, 1u);
                SLOT_INS(s0.z, n0, kb0, 2u); SLOT_INS(s0.w, n0, kb0, 3u);
            }
            if (n1) {
                SLOT_INS(s1.x, n1, kb1, 0u); SLOT_INS(s1.y, n1, kb1, 1u);
                SLOT_INS(s1.z, n1, kb1, 2u); SLOT_INS(s1.w, n1, kb1, 3u);
            }
            if (__any((n0 > 4u) | (n1 > 4u))) {          // essentially never
                #pragma unroll
                for (uint32_t m = 4; m < 8; ++m) {
                    if (m < n0) {
                        const uint32_t kk = kb0 | slots[(size_t)cell0 * kSlotK + m];
                        INSERT5(l0, l1, l2, l3, l4, kk);
                    }
                    if (m < n1) {
                        const uint32_t kk = kb1 | slots[(size_t)cell1 * kSlotK + m];
                        INSERT5(l0, l1, l2, l3, l4, kk);
                    }
                }
            }
            #undef SLOT_INS
            waveMerge5_(l0, l1, l2, l3, l4);             // chunk-global top-5
            merge5_(g0, g1, g2, g3, g4, l0, l1, l2, l3, l4);
        }
    }

    // ---- fold in overflow points (cells that spilled past 8 slots) ----
    const uint32_t ovf = ovfCnt[b];
    if (ovf > (uint32_t)kOvfCap) {
        // unreachable in practice; exact full rescan
        const int* cb = coords_b + (size_t)b * kNb * 3;
        uint32_t t0 = 0xFFFFFFFFu, t1 = t0, t2 = t0, t3 = t0, t4 = t0;
        for (int j = lane; j < kNb; j += 64) {
            const int dx = ax - cb[3 * j + 0];
            const int dy = ay - cb[3 * j + 1];
            const int dz = az - cb[3 * j + 2];
            const uint32_t d2 = (uint32_t)(dx * dx + dy * dy + dz * dz);
            INSERT5(t0, t1, t2, t3, t4, (d2 << 13) | (uint32_t)j);
        }
        waveMerge5_(t0, t1, t2, t3, t4);
        g0 = t0; g1 = t1; g2 = t2; g3 = t3; g4 = t4;
    } else {
        if (ovf > 0) {
            const int* cb = coords_b + (size_t)b * kNb * 3;
            uint32_t l0 = 0xFFFFFFFFu, l1 = l0, l2 = l0, l3 = l0, l4 = l0;
            for (uint32_t i = (uint32_t)lane; i < ovf; i += 64) {
                const uint32_t j = ovfIdx[b * kOvfCap + i];
                const int dx = ax - cb[3 * j + 0];
                const int dy = ay - cb[3 * j + 1];
                const int dz = az - cb[3 * j + 2];
                const uint32_t d2 = (uint32_t)(dx * dx + dy * dy + dz * dz);
                INSERT5(l0, l1, l2, l3, l4, (d2 << 13) | j);
            }
            waveMerge5_(l0, l1, l2, l3, l4);
            merge5_(g0, g1, g2, g3, g4, l0, l1, l2, l3, l4);
        }
        if ((g4 >> 13) > (uint32_t)kDMax) {
            // < 5 points within d<=8 of this row (prob ~0): exact rescan
            const int* cb = coords_b + (size_t)b * kNb * 3;
            uint32_t t0 = 0xFFFFFFFFu, t1 = t0, t2 = t0, t3 = t0, t4 = t0;
            for (int j = lane; j < kNb; j += 64) {
                const int dx = ax - cb[3 * j + 0];
                const int dy = ay - cb[3 * j + 1];
                const int dz = az - cb[3 * j + 2];
                const uint32_t d2 = (uint32_t)(dx * dx + dy * dy + dz * dz);
                INSERT5(t0, t1, t2, t3, t4, (d2 << 13) | (uint32_t)j);
            }
            waveMerge5_(t0, t1, t2, t3, t4);
            g0 = t0; g1 = t1; g2 = t2; g3 = t3; g4 = t4;
        }
    }

    // ---- weights + gather: lane == channel ----
    const float* fb = feat_b + (size_t)b * kNb * kC;
    const uint32_t keys[5] = {g0, g1, g2, g3, g4};
    float acc = 0.0f;
    #pragma unroll
    for (int t = 0; t < 5; ++t) {
        const uint32_t key = keys[t];
        const int j = (int)(key & 8191u);
        const float dist = sqrtf((float)(key >> 13)) * (1.0f / 32.0f);
        const float w = 0.5f - fminf(dist, 0.5f);
        acc += w * fb[(size_t)j * kC + lane];             // coalesced 256B/row
    }

    const size_t orow = ((size_t)b * kNa + row) * (2 * kC);
    out[orow + lane] = feat_a[((size_t)b * kNa + row) * kC + lane];
    out[orow + kC + lane] = acc;
}

// ---------------- brute kernel (fallback if ws too small) ----------------

__global__ __launch_bounds__(512, 8)
void dist_match_brute(const int* __restrict__ coords_a,
                      const int* __restrict__ coords_b,
                      const float* __restrict__ feat_a,
                      const float* __restrict__ feat_b,
                      float* __restrict__ out)
{
    __shared__ int spack[kNb];
    const int b = blockIdx.x >> 10;
    const int rowBase = (blockIdx.x & 1023) * 8;
    const int tid = threadIdx.x;
    const int lane = tid & 63;
    const int wave = tid >> 6;

    const int* cb = coords_b + (size_t)b * kNb * 3;
    for (int j = tid; j < kNb; j += 512) {
        spack[j] = cb[3 * j + 0] | (cb[3 * j + 1] << 8) | (cb[3 * j + 2] << 16);
    }
    __syncthreads();

    const int row = rowBase + wave;
    const int* ca = coords_a + ((size_t)b * kNa + row) * 3;
    const int ax = ca[0], ay = ca[1], az = ca[2];
    const int a2 = ax * ax + ay * ay + az * az;
    const int paneg2 = ((-2 * ax) & 255) | (((-2 * ay) & 255) << 8)
                     | (((-2 * az) & 255) << 16);

    uint32_t t0 = 0xFFFFFFFFu, t1 = t0, t2 = t0, t3 = t0, t4 = t0;
    for (int k = 0; k < kNb / 256; ++k) {
        const int baseI = k * 256 + lane * 4;
        const int4 p4 = *reinterpret_cast<const int4*>(spack + baseI);
        const int ps[4] = {p4.x, p4.y, p4.z, p4.w};
        #pragma unroll
        for (int u = 0; u < 4; ++u) {
            const int p = ps[u];
            const int dot1 = __builtin_amdgcn_sdot4(paneg2, p, a2, false);
            const int d2 = __builtin_amdgcn_sdot4(p, p, dot1, false);
            const uint32_t key = ((uint32_t)d2 << 13) | (uint32_t)(baseI + u);
            INSERT5(t0, t1, t2, t3, t4, key);
        }
    }
    waveMerge5_(t0, t1, t2, t3, t4);
    const float* fb = feat_b + (size_t)b * kNb * kC;
    const uint32_t keys[5] = {t0, t1, t2, t3, t4};
    float acc = 0.0f;
    #pragma unroll
    for (int t = 0; t < 5; ++t) {
        const uint32_t key = keys[t];
        const int j = (int)(key & 8191u);
        const float dist = sqrtf((float)(key >> 13)) * (1.0f / 32.0f);
        const float w = 0.5f - fminf(dist, 0.5f);
        acc += w * fb[(size_t)j * kC + lane];
    }
    const size_t orow = ((size_t)b * kNa + row) * (2 * kC);
    out[orow + lane] = feat_a[((size_t)b * kNa + row) * kC + lane];
    out[orow + kC + lane] = acc;
}

extern "C" void kernel_launch(void* const* d_in, const int* in_sizes, int n_in,
                              void* d_out, int out_size, void* d_ws, size_t ws_size,
                              hipStream_t stream) {
    const int* coords_a = (const int*)d_in[0];
    const int* coords_b = (const int*)d_in[1];
    const float* feat_a = (const float*)d_in[2];
    const float* feat_b = (const float*)d_in[3];
    float* out = (float*)d_out;

    if (ws_size < kWsBytes) {
        dist_match_brute<<<kB * 1024, 512, 0, stream>>>(coords_a, coords_b,
                                                        feat_a, feat_b, out);
        return;
    }

    uint32_t* ws32 = (uint32_t*)d_ws;
    uint32_t* cnt    = ws32 + kCntOff;
    uint32_t* ovfCnt = ws32 + kOvfCntOff;
    uint32_t* ovfIdx = ws32 + kOvfIdxOff;
    uint32_t* slots  = ws32 + kSlotOff;

    k_clear<<<kClrBlocks, 256, 0, stream>>>((uint4*)d_ws);   // cnt + ovfCnt
    k_scatter<<<kB * kNb / 256, 256, 0, stream>>>(coords_b, cnt, slots,
                                                  ovfCnt, ovfIdx);
    dist_match_bucket<<<kB * 1024, 512, 0, stream>>>(coords_a, coords_b,
                                                     feat_a, feat_b,
                                                     cnt, slots, ovfCnt, ovfIdx,
                                                     out);
}

// Round 8
// 37.561 us; speedup vs baseline: 4.5812x; 1.0808x over previous
//
#include <hip/hip_runtime.h>
#include <stdint.h>

// DistMatchLayer via spatial bucketing, round 8.
// Changes vs round 7 (both targeting the main kernel's issue+latency mix):
//  1. slotLo sentinel encoding: slotLo[cell] (4 words) cleared to 0xFFFFFFFF;
//     main reads ONLY the 16B slot vector per cell (cnt removed from the
//     dependent chain). Key build is kb|word -- OR with sentinel 0xFFFFFFFF
//     stays sentinel, so empty slots cost zero predication ops. Cells with
//     >4 points detected from the vector itself (all 4 valid, P~1.6%/row)
//     -> rare branch reads cnt + slotHi. Exact in all cases.
//  2. Per-chunk butterfly merge (204 VALU + 30 shfl) replaced by 5-round
//     wave-min extract (60 VALU + 30 shfl): round r takes the wave-min of
//     lane list heads (unique keys -> one lane advances), yielding the
//     chunk's sorted global top-5, then merge5_ into g.
// Exactness/stability unchanged: full keys (d2<<13)|j, order-independent
// top-5-of-union, early exit only when next chunk min d2 > g4>>13, overflow
// list + brute fallback close every corner case.

namespace {
constexpr int kB = 4;
constexpr int kNa = 8192;
constexpr int kNb = 8192;
constexpr int kC = 64;

constexpr int kRad = 8;                 // offsets |d| <= 8, d2 <= 64
constexpr int kDMax = 64;
constexpr int kGrid = 48;               // 32 + 2*8 padded grid
constexpr int kGrid2 = kGrid * kGrid;   // 2304
constexpr int kGrid3 = kGrid2 * kGrid;  // 110592
constexpr int kOff = kRad * kGrid2 + kRad * kGrid + kRad;  // 19208

constexpr int kTabCap = 4992;           // 39 macro-chunks of 128 (ball(8)=2109)
constexpr int kMacro = kTabCap / 128;   // 39

constexpr int kOvfCap = 256;

// ws layout (u32 words)
constexpr size_t kCntOff    = 0;                                     // [442368]
constexpr size_t kOvfCntOff = 442368;                                // [4]
constexpr size_t kOvfIdxOff = 442372;                                // [1024]
constexpr size_t kSlotLoOff = 443396;                                // 16B-aligned
constexpr size_t kSlotHiOff = kSlotLoOff + (size_t)kB * kGrid3 * 4;  // 2212868
constexpr size_t kWsWords   = kSlotHiOff + (size_t)kB * kGrid3 * 4;  // 3982340
constexpr size_t kWsBytes   = kWsWords * 4ull;                       // ~15.9 MB

// clear ranges in uint4 units: [0,kZeroVecEnd) -> 0 (cnt+ovfCnt),
// [kFFVecBeg,kFFVecEnd) -> 0xFF (slotLo). slotHi/ovfIdx need no clearing.
constexpr int kZeroVecEnd = (int)((kOvfCntOff + 4) / 4);   // 110593
constexpr int kFFVecBeg   = (int)(kSlotLoOff / 4);         // 110849
constexpr int kFFVecEnd   = (int)(kSlotHiOff / 4);         // 553217
constexpr int kClrBlocks  = (kFFVecEnd + 255) / 256;       // 2161

struct Tab { uint32_t e[kTabCap]; uint32_t n; };
constexpr Tab buildTab() {
    Tab t{};
    int cnt[kDMax + 1] = {};
    for (int dx = -kRad; dx <= kRad; ++dx)
        for (int dy = -kRad; dy <= kRad; ++dy)
            for (int dz = -kRad; dz <= kRad; ++dz) {
                const int d2 = dx * dx + dy * dy + dz * dz;
                if (d2 <= kDMax) cnt[d2]++;
            }
    int pos[kDMax + 1] = {};
    int run = 0;
    for (int d = 0; d <= kDMax; ++d) { pos[d] = run; run += cnt[d]; }
    for (int dx = -kRad; dx <= kRad; ++dx)
        for (int dy = -kRad; dy <= kRad; ++dy)
            for (int dz = -kRad; dz <= kRad; ++dz) {
                const int d2 = dx * dx + dy * dy + dz * dz;
                if (d2 <= kDMax) {
                    const int sd = dx * kGrid2 + dy * kGrid + dz + kOff;
                    t.e[pos[d2]++] = ((uint32_t)d2 << 18) | (uint32_t)sd;
                }
            }
    t.n = (uint32_t)run;
    for (int i = run; i < kTabCap; ++i) t.e[i] = 0x7FFFFFFFu;  // sentinel
    return t;
}
__device__ constexpr Tab kTab = buildTab();   // ~20 KB .rodata
}  // namespace

__device__ __forceinline__ uint32_t umin_(uint32_t a, uint32_t b) { return a < b ? a : b; }
__device__ __forceinline__ uint32_t umax_(uint32_t a, uint32_t b) { return a > b ? a : b; }

#define INSERT5(T0, T1, T2, T3, T4, KEY) do {                 \
    const uint32_t m0_ = umax_(T0, KEY); T0 = umin_(T0, KEY); \
    const uint32_t m1_ = umax_(T1, m0_); T1 = umin_(T1, m0_); \
    const uint32_t m2_ = umax_(T2, m1_); T2 = umin_(T2, m1_); \
    const uint32_t m3_ = umax_(T3, m2_); T3 = umin_(T3, m2_); \
    T4 = umin_(T4, m3_); } while (0)

__device__ __forceinline__ void merge5_(uint32_t& t0, uint32_t& t1, uint32_t& t2,
                                        uint32_t& t3, uint32_t& t4,
                                        uint32_t b0, uint32_t b1, uint32_t b2,
                                        uint32_t b3, uint32_t b4) {
    const uint32_t c0 = umin_(t0, b0);
    const uint32_t c1 = umin_(umin_(umax_(t0, b0), t1), b1);
    const uint32_t c2 = umin_(umin_(umax_(t0, b1), umax_(t1, b0)), umin_(t2, b2));
    const uint32_t c3 = umin_(umin_(umax_(t0, b2), umax_(t1, b1)),
                              umin_(umax_(t2, b0), umin_(t3, b3)));
    const uint32_t c4 = umin_(umin_(umax_(t0, b3), umax_(t1, b2)),
                              umin_(umin_(umax_(t2, b1), umax_(t3, b0)),
                                    umin_(t4, b4)));
    t0 = c0; t1 = c1; t2 = c2; t3 = c3; t4 = c4;
}

// butterfly: all 64 lanes end with the wave-global sorted top-5 (rare paths)
__device__ __forceinline__ void waveMerge5_(uint32_t& t0, uint32_t& t1, uint32_t& t2,
                                            uint32_t& t3, uint32_t& t4) {
    #pragma unroll
    for (int s = 1; s < 64; s <<= 1) {
        const uint32_t b0 = (uint32_t)__shfl_xor((int)t0, s);
        const uint32_t b1 = (uint32_t)__shfl_xor((int)t1, s);
        const uint32_t b2 = (uint32_t)__shfl_xor((int)t2, s);
        const uint32_t b3 = (uint32_t)__shfl_xor((int)t3, s);
        const uint32_t b4 = (uint32_t)__shfl_xor((int)t4, s);
        merge5_(t0, t1, t2, t3, t4, b0, b1, b2, b3, b4);
    }
}

#define WAVE_MIN_U32(DST, SRC) do {                          \
    uint32_t m_ = (SRC);                                     \
    m_ = umin_(m_, (uint32_t)__shfl_xor((int)m_, 1));        \
    m_ = umin_(m_, (uint32_t)__shfl_xor((int)m_, 2));        \
    m_ = umin_(m_, (uint32_t)__shfl_xor((int)m_, 4));        \
    m_ = umin_(m_, (uint32_t)__shfl_xor((int)m_, 8));        \
    m_ = umin_(m_, (uint32_t)__shfl_xor((int)m_, 16));       \
    m_ = umin_(m_, (uint32_t)__shfl_xor((int)m_, 32));       \
    (DST) = m_; } while (0)

// one extract round: Q = global min of remaining; owning lane advances list
#define EXTRACT_ROUND(Q) do {                                \
    WAVE_MIN_U32(Q, l0);                                     \
    const bool adv_ = (l0 == (Q));                           \
    l0 = adv_ ? l1 : l0; l1 = adv_ ? l2 : l1;                \
    l2 = adv_ ? l3 : l2; l3 = adv_ ? l4 : l3;                \
    l4 = adv_ ? 0xFFFFFFFFu : l4; } while (0)

// ---------------- clear + scatter ----------------

__global__ __launch_bounds__(256)
void k_clear(uint4* __restrict__ ws) {
    const int i = blockIdx.x * 256 + threadIdx.x;
    if (i < kZeroVecEnd) ws[i] = uint4{0u, 0u, 0u, 0u};
    else if (i >= kFFVecBeg && i < kFFVecEnd) ws[i] = uint4{~0u, ~0u, ~0u, ~0u};
}

__global__ void k_scatter(const int* __restrict__ coords_b,
                          uint32_t* __restrict__ cnt,
                          uint32_t* __restrict__ slotLo,
                          uint32_t* __restrict__ slotHi,
                          uint32_t* __restrict__ ovfCnt,
                          uint32_t* __restrict__ ovfIdx) {
    const int i = blockIdx.x * blockDim.x + threadIdx.x;
    if (i >= kB * kNb) return;
    const int b = i >> 13;
    const int j = i & (kNb - 1);
    const int* p = coords_b + (size_t)i * 3;
    const int cell = b * kGrid3
                   + (p[0] + kRad) * kGrid2 + (p[1] + kRad) * kGrid + (p[2] + kRad);
    const uint32_t pos = atomicAdd(&cnt[cell], 1u);
    if (pos < 4u) {
        slotLo[(size_t)cell * 4 + pos] = (uint32_t)j;
    } else if (pos < 8u) {
        slotHi[(size_t)cell * 4 + (pos - 4u)] = (uint32_t)j;
    } else {
        const uint32_t op = atomicAdd(&ovfCnt[b], 1u);
        if (op < (uint32_t)kOvfCap) ovfIdx[b * kOvfCap + op] = (uint32_t)j;
    }
}

// ---------------- main kernel: wave-per-row shell search ----------------

__global__ __launch_bounds__(512, 8)
void dist_match_bucket(const int* __restrict__ coords_a,
                       const int* __restrict__ coords_b,
                       const float* __restrict__ feat_a,
                       const float* __restrict__ feat_b,
                       const uint32_t* __restrict__ cnt,
                       const uint32_t* __restrict__ slotLo,
                       const uint32_t* __restrict__ slotHi,
                       const uint32_t* __restrict__ ovfCnt,
                       const uint32_t* __restrict__ ovfIdx,
                       float* __restrict__ out)
{
    const int b = blockIdx.x >> 10;                // 1024 blocks/batch
    const int rowBase = (blockIdx.x & 1023) * 8;
    const int lane = threadIdx.x & 63;
    const int wave = threadIdx.x >> 6;
    const int row = rowBase + wave;

    const int* ca = coords_a + ((size_t)b * kNa + row) * 3;
    const int ax = ca[0], ay = ca[1], az = ca[2];
    const int aCell = (ax + kRad) * kGrid2 + (ay + kRad) * kGrid + (az + kRad);
    const int base = b * kGrid3 + aCell - kOff;

    // persistent global top-5 (same on all lanes; g4 == exact 5th-best-so-far)
    uint32_t g0 = 0xFFFFFFFFu, g1 = g0, g2 = g0, g3 = g0, g4 = g0;

    for (int c = 0; c < kMacro; ++c) {
        const uint32_t cd2 = kTab.e[c * 128] >> 18;      // uniform (sorted)
        if (cd2 > (g4 >> 13)) break;                     // provably can't improve
        const uint32_t e0 = kTab.e[c * 128 + lane];
        const uint32_t e1 = kTab.e[c * 128 + 64 + lane];
        const uint32_t d20 = e0 >> 18, d21 = e1 >> 18;
        const int cell0 = base + (int)(e0 & 0x3FFFFu);
        const int cell1 = base + (int)(e1 & 0x3FFFFu);
        // slot vectors; sentinel 0xFFFFFFFF words OR into sentinel keys
        uint4 s0 = uint4{~0u, ~0u, ~0u, ~0u};
        uint4 s1 = uint4{~0u, ~0u, ~0u, ~0u};
        if (d20 <= (uint32_t)kDMax)
            s0 = *reinterpret_cast<const uint4*>(slotLo + (size_t)cell0 * 4);
        if (d21 <= (uint32_t)kDMax)
            s1 = *reinterpret_cast<const uint4*>(slotLo + (size_t)cell1 * 4);

        const uint32_t kb0 = d20 << 13, kb1 = d21 << 13;
        uint32_t l0 = 0xFFFFFFFFu, l1 = l0, l2 = l0, l3 = l0, l4 = l0;
        INSERT5(l0, l1, l2, l3, l4, kb0 | s0.x);
        INSERT5(l0, l1, l2, l3, l4, kb0 | s0.y);
        INSERT5(l0, l1, l2, l3, l4, kb0 | s0.z);
        INSERT5(l0, l1, l2, l3, l4, kb0 | s0.w);
        INSERT5(l0, l1, l2, l3, l4, kb1 | s1.x);
        INSERT5(l0, l1, l2, l3, l4, kb1 | s1.y);
        INSERT5(l0, l1, l2, l3, l4, kb1 | s1.z);
        INSERT5(l0, l1, l2, l3, l4, kb1 | s1.w);

        // cells with all 4 lo-slots valid may hold >4 points (P ~ 1.6%/row)
        const uint32_t mx0 = umax_(umax_(s0.x, s0.y), umax_(s0.z, s0.w));
        const uint32_t mx1 = umax_(umax_(s1.x, s1.y), umax_(s1.z, s1.w));
        if (__any((mx0 != ~0u) || (mx1 != ~0u))) {
            if (mx0 != ~0u) {
                const uint32_t n = umin_(cnt[cell0], 8u);
                for (uint32_t m = 4; m < n; ++m)
                    INSERT5(l0, l1, l2, l3, l4,
                            kb0 | slotHi[(size_t)cell0 * 4 + (m - 4u)]);
            }
            if (mx1 != ~0u) {
                const uint32_t n = umin_(cnt[cell1], 8u);
                for (uint32_t m = 4; m < n; ++m)
                    INSERT5(l0, l1, l2, l3, l4,
                            kb1 | slotHi[(size_t)cell1 * 4 + (m - 4u)]);
            }
        }

        if (__any(l0 != 0xFFFFFFFFu)) {                  // chunk non-empty
            // extract the chunk's sorted global top-5, merge into g
            uint32_t q0, q1, q2, q3, q4;
            EXTRACT_ROUND(q0);
            EXTRACT_ROUND(q1);
            EXTRACT_ROUND(q2);
            EXTRACT_ROUND(q3);
            EXTRACT_ROUND(q4);
            merge5_(g0, g1, g2, g3, g4, q0, q1, q2, q3, q4);
        }
    }

    // ---- fold in overflow points (cells that spilled past 8 slots) ----
    const uint32_t ovf = ovfCnt[b];
    if (ovf > (uint32_t)kOvfCap) {
        // unreachable in practice; exact full rescan
        const int* cb = coords_b + (size_t)b * kNb * 3;
        uint32_t t0 = 0xFFFFFFFFu, t1 = t0, t2 = t0, t3 = t0, t4 = t0;
        for (int j = lane; j < kNb; j += 64) {
            const int dx = ax - cb[3 * j + 0];
            const int dy = ay - cb[3 * j + 1];
            const int dz = az - cb[3 * j + 2];
            const uint32_t d2 = (uint32_t)(dx * dx + dy * dy + dz * dz);
            INSERT5(t0, t1, t2, t3, t4, (d2 << 13) | (uint32_t)j);
        }
        waveMerge5_(t0, t1, t2, t3, t4);
        g0 = t0; g1 = t1; g2 = t2; g3 = t3; g4 = t4;
    } else {
        if (ovf > 0) {
            const int* cb = coords_b + (size_t)b * kNb * 3;
            uint32_t l0 = 0xFFFFFFFFu, l1 = l0, l2 = l0, l3 = l0, l4 = l0;
            for (uint32_t i = (uint32_t)lane; i < ovf; i += 64) {
                const uint32_t j = ovfIdx[b * kOvfCap + i];
                const int dx = ax - cb[3 * j + 0];
                const int dy = ay - cb[3 * j + 1];
                const int dz = az - cb[3 * j + 2];
                const uint32_t d2 = (uint32_t)(dx * dx + dy * dy + dz * dz);
                INSERT5(l0, l1, l2, l3, l4, (d2 << 13) | j);
            }
            waveMerge5_(l0, l1, l2, l3, l4);
            merge5_(g0, g1, g2, g3, g4, l0, l1, l2, l3, l4);
        }
        if ((g4 >> 13) > (uint32_t)kDMax) {
            // < 5 points within d<=8 of this row (prob ~0): exact rescan
            const int* cb = coords_b + (size_t)b * kNb * 3;
            uint32_t t0 = 0xFFFFFFFFu, t1 = t0, t2 = t0, t3 = t0, t4 = t0;
            for (int j = lane; j < kNb; j += 64) {
                const int dx = ax - cb[3 * j + 0];
                const int dy = ay - cb[3 * j + 1];
                const int dz = az - cb[3 * j + 2];
                const uint32_t d2 = (uint32_t)(dx * dx + dy * dy + dz * dz);
                INSERT5(t0, t1, t2, t3, t4, (d2 << 13) | (uint32_t)j);
            }
            waveMerge5_(t0, t1, t2, t3, t4);
            g0 = t0; g1 = t1; g2 = t2; g3 = t3; g4 = t4;
        }
    }

    // ---- weights + gather: lane == channel ----
    const float* fb = feat_b + (size_t)b * kNb * kC;
    const uint32_t keys[5] = {g0, g1, g2, g3, g4};
    float acc = 0.0f;
    #pragma unroll
    for (int t = 0; t < 5; ++t) {
        const uint32_t key = keys[t];
        const int j = (int)(key & 8191u);
        const float dist = sqrtf((float)(key >> 13)) * (1.0f / 32.0f);
        const float w = 0.5f - fminf(dist, 0.5f);
        acc += w * fb[(size_t)j * kC + lane];             // coalesced 256B/row
    }

    const size_t orow = ((size_t)b * kNa + row) * (2 * kC);
    out[orow + lane] = feat_a[((size_t)b * kNa + row) * kC + lane];
    out[orow + kC + lane] = acc;
}

// ---------------- brute kernel (fallback if ws too small) ----------------

__global__ __launch_bounds__(512, 8)
void dist_match_brute(const int* __restrict__ coords_a,
                      const int* __restrict__ coords_b,
                      const float* __restrict__ feat_a,
                      const float* __restrict__ feat_b,
                      float* __restrict__ out)
{
    __shared__ int spack[kNb];
    const int b = blockIdx.x >> 10;
    const int rowBase = (blockIdx.x & 1023) * 8;
    const int tid = threadIdx.x;
    const int lane = tid & 63;
    const int wave = tid >> 6;

    const int* cb = coords_b + (size_t)b * kNb * 3;
    for (int j = tid; j < kNb; j += 512) {
        spack[j] = cb[3 * j + 0] | (cb[3 * j + 1] << 8) | (cb[3 * j + 2] << 16);
    }
    __syncthreads();

    const int row = rowBase + wave;
    const int* ca = coords_a + ((size_t)b * kNa + row) * 3;
    const int ax = ca[0], ay = ca[1], az = ca[2];
    const int a2 = ax * ax + ay * ay + az * az;
    const int paneg2 = ((-2 * ax) & 255) | (((-2 * ay) & 255) << 8)
                     | (((-2 * az) & 255) << 16);

    uint32_t t0 = 0xFFFFFFFFu, t1 = t0, t2 = t0, t3 = t0, t4 = t0;
    for (int k = 0; k < kNb / 256; ++k) {
        const int baseI = k * 256 + lane * 4;
        const int4 p4 = *reinterpret_cast<const int4*>(spack + baseI);
        const int ps[4] = {p4.x, p4.y, p4.z, p4.w};
        #pragma unroll
        for (int u = 0; u < 4; ++u) {
            const int p = ps[u];
            const int dot1 = __builtin_amdgcn_sdot4(paneg2, p, a2, false);
            const int d2 = __builtin_amdgcn_sdot4(p, p, dot1, false);
            const uint32_t key = ((uint32_t)d2 << 13) | (uint32_t)(baseI + u);
            INSERT5(t0, t1, t2, t3, t4, key);
        }
    }
    waveMerge5_(t0, t1, t2, t3, t4);
    const float* fb = feat_b + (size_t)b * kNb * kC;
    const uint32_t keys[5] = {t0, t1, t2, t3, t4};
    float acc = 0.0f;
    #pragma unroll
    for (int t = 0; t < 5; ++t) {
        const uint32_t key = keys[t];
        const int j = (int)(key & 8191u);
        const float dist = sqrtf((float)(key >> 13)) * (1.0f / 32.0f);
        const float w = 0.5f - fminf(dist, 0.5f);
        acc += w * fb[(size_t)j * kC + lane];
    }
    const size_t orow = ((size_t)b * kNa + row) * (2 * kC);
    out[orow + lane] = feat_a[((size_t)b * kNa + row) * kC + lane];
    out[orow + kC + lane] = acc;
}

extern "C" void kernel_launch(void* const* d_in, const int* in_sizes, int n_in,
                              void* d_out, int out_size, void* d_ws, size_t ws_size,
                              hipStream_t stream) {
    const int* coords_a = (const int*)d_in[0];
    const int* coords_b = (const int*)d_in[1];
    const float* feat_a = (const float*)d_in[2];
    const float* feat_b = (const float*)d_in[3];
    float* out = (float*)d_out;

    if (ws_size < kWsBytes) {
        dist_match_brute<<<kB * 1024, 512, 0, stream>>>(coords_a, coords_b,
                                                        feat_a, feat_b, out);
        return;
    }

    uint32_t* ws32 = (uint32_t*)d_ws;
    uint32_t* cnt    = ws32 + kCntOff;
    uint32_t* ovfCnt = ws32 + kOvfCntOff;
    uint32_t* ovfIdx = ws32 + kOvfIdxOff;
    uint32_t* slotLo = ws32 + kSlotLoOff;
    uint32_t* slotHi = ws32 + kSlotHiOff;

    k_clear<<<kClrBlocks, 256, 0, stream>>>((uint4*)d_ws);
    k_scatter<<<kB * kNb / 256, 256, 0, stream>>>(coords_b, cnt, slotLo, slotHi,
                                                  ovfCnt, ovfIdx);
    dist_match_bucket<<<kB * 1024, 512, 0, stream>>>(coords_a, coords_b,
                                                     feat_a, feat_b,
                                                     cnt, slotLo, slotHi,
                                                     ovfCnt, ovfIdx, out);
}